// Round 15
// baseline (354.812 us; speedup 1.0000x reference)
//
#include <hip/hip_runtime.h>

typedef __attribute__((ext_vector_type(4))) float f32x4;
typedef __attribute__((ext_vector_type(8))) __bf16 bf16x8;
typedef __attribute__((ext_vector_type(4))) unsigned short us4;
typedef __attribute__((ext_vector_type(8))) unsigned short us8;

#define DEVI static __device__ __forceinline__

DEVI unsigned short f2bf(float f){
  union { float f; unsigned u; } x; x.f = f;
  unsigned r = x.u + 0x7fffu + ((x.u >> 16) & 1u);
  return (unsigned short)(r >> 16);
}
DEVI float bf2f(unsigned short h){
  union { unsigned u; float f; } x; x.u = ((unsigned)h) << 16;
  return x.f;
}

typedef __attribute__((address_space(1))) unsigned int gu32;
typedef __attribute__((address_space(3))) unsigned int lu32;
DEVI void gll16(const void* g, void* l){
  __builtin_amdgcn_global_load_lds((gu32*)g, (lu32*)l, 16, 0, 0);
}

DEVI f32x4 mfma16(bf16x8 a, bf16x8 b, f32x4 c){
  return __builtin_amdgcn_mfma_f32_16x16x32_bf16(a, b, c, 0, 0, 0);
}

DEVI float wredsum(float v){
  #pragma unroll
  for (int m = 1; m < 64; m <<= 1) v += __shfl_xor(v, m);
  return v;
}

// ---------------- weight prep (merged) ----------------
__global__ __launch_bounds__(256) void conv_w_prep2(const float* __restrict__ w1,
                                                    const float* __restrict__ w2,
                                                    unsigned short* __restrict__ wp1,
                                                    unsigned short* __restrict__ wp2){
  int idx = blockIdx.x * 256 + threadIdx.x;            // over 2*C*C
  int sel = idx >> 20;
  int lo  = idx & 1048575;
  const float* p = (sel ? w2 : w1) + (size_t)lo * 3;
  unsigned short* wp = sel ? wp2 : wp1;
  wp[lo]           = f2bf(p[0]);
  wp[1048576 + lo] = f2bf(p[1]);
  wp[2097152 + lo] = f2bf(p[2]);
}

__global__ __launch_bounds__(256) void cast_f2b2(const float* __restrict__ qw,
                                                 const float* __restrict__ pw,
                                                 unsigned short* __restrict__ qo,
                                                 unsigned short* __restrict__ po){
  int idx = blockIdx.x * 256 + threadIdx.x;            // 1048576 quads
  const float* src; unsigned short* dst; int lo;
  if (idx < 786432){ src = qw; dst = qo; lo = idx; }
  else             { src = pw; dst = po; lo = idx - 786432; }
  f32x4 v = *(const f32x4*)&src[(size_t)lo * 4];
  us4 o;
  #pragma unroll
  for (int j = 0; j < 4; j++) o[j] = f2bf(v[j]);
  *(us4*)&dst[(size_t)lo * 4] = o;
}

// blocks 0..63: zero pads; blocks 64..191: btab (pre-scaled by 8*log2e)
__global__ __launch_bounds__(256) void misc_prep(unsigned short* __restrict__ h1p,
                                                 unsigned short* __restrict__ g2p,
                                                 const float* __restrict__ emb,
                                                 float* __restrict__ btab){
  int bid = blockIdx.x;
  if (bid < 64){
    int idx = bid * 256 + threadIdx.x;                 // 16384
    int b = idx >> 11, rr = (idx >> 10) & 1, c = idx & 1023;
    size_t off = ((size_t)b * 1026 + (rr ? 1025 : 0)) * 1024 + c;
    h1p[off] = 0; g2p[off] = 0;
  } else {
    int idx = (bid - 64) * 256 + threadIdx.x;
    if (idx >= 2047 * 16) return;
    int d = idx >> 4, h = idx & 15;
    int n0 = d - 1023;
    int ret = (n0 < 0) ? 16 : 0;
    int n = (n0 < 0) ? -n0 : n0;
    int bucket;
    if (n < 8) bucket = ret + n;
    else {
      float ratio = logf((float)n * 0.125f) / 2.0794415416798357f;
      int vl = 8 + (int)(ratio * 8.0f);
      bucket = ret + (vl < 15 ? vl : 15);
    }
    btab[h * 2048 + d] = emb[bucket * 16 + h] * 11.541560327111707f;
  }
}

// ---------------- GN1 stats on fp32 + cast x -> bf16 (xb) ----------------
__global__ __launch_bounds__(256) void gn_stats_cast(const float* __restrict__ in,
                                                     float2* __restrict__ st,
                                                     unsigned short* __restrict__ xb){
  const int g = blockIdx.x; const int tid = threadIdx.x;
  const float* p = in + (size_t)g * 32768;
  unsigned short* q = xb + (size_t)g * 32768;
  float s = 0.f, s2 = 0.f;
  for (int i = tid * 4; i < 32768; i += 1024){
    f32x4 v = *(const f32x4*)&p[i];
    us4 o;
    #pragma unroll
    for (int j = 0; j < 4; j++){ s += v[j]; s2 += v[j] * v[j]; o[j] = f2bf(v[j]); }
    *(us4*)&q[i] = o;
  }
  s = wredsum(s); s2 = wredsum(s2);
  __shared__ float rs[4], rs2[4];
  if ((tid & 63) == 0){ rs[tid >> 6] = s; rs2[tid >> 6] = s2; }
  __syncthreads();
  if (tid == 0){
    float S = rs[0] + rs[1] + rs[2] + rs[3];
    float S2 = rs2[0] + rs2[1] + rs2[2] + rs2[3];
    float m = S * (1.f / 32768.f);
    float var = S2 * (1.f / 32768.f) - m * m;
    st[g] = make_float2(m, rsqrtf(var + 1e-5f));
  }
}

// C-major input -> T-major bf16 output (transpose through LDS), optional SiLU, optional padded rows
// FROMPART==1: st points at GN32 partials emitted by gn8_apply (reduce 4 on the fly)
template<int SILU, int INBF16, int OUTPAD, int FROMPART>
__global__ __launch_bounds__(256) void gn_apply_tr(
    const void* __restrict__ inp, const float2* __restrict__ st,
    const float* __restrict__ gma, const float* __restrict__ bta,
    unsigned short* __restrict__ out)
{
  const int gid = blockIdx.x;                 // b(3b) g(5b) tc(4b)
  const int tc = gid & 15, g = (gid >> 4) & 31, b = gid >> 9;
  const int tid = threadIdx.x;
  const int t0 = tc * 64;
  __shared__ __align__(16) unsigned short tr[64 * 40];
  float2 s;
  if (FROMPART){
    int g8 = g >> 2, k = g & 3;
    float S = 0.f, S2 = 0.f;
    #pragma unroll
    for (int j = 0; j < 4; j++){
      float2 v = st[(size_t)(b * 8 + g8) * 16 + k * 4 + j];
      S += v.x; S2 += v.y;
    }
    float m = S * (1.f / 32768.f);
    float var = S2 * (1.f / 32768.f) - m * m;
    s = make_float2(m, rsqrtf(var + 1e-5f));
  } else {
    s = st[b * 32 + g];
  }
  int c = tid >> 3, t8 = (tid & 7) * 8;
  int ch = g * 32 + c;
  float sc = gma[ch] * s.y;
  float sh = bta[ch] - s.x * sc;
  float vv[8];
  if (INBF16){
    const unsigned short* p = (const unsigned short*)inp + ((size_t)b * 1024 + ch) * 1024 + t0 + t8;
    us8 v = *(const us8*)p;
    #pragma unroll
    for (int j = 0; j < 8; j++) vv[j] = bf2f(v[j]);
  } else {
    const float* p = (const float*)inp + ((size_t)b * 1024 + ch) * 1024 + t0 + t8;
    f32x4 v0 = *(const f32x4*)p; f32x4 v1 = *(const f32x4*)(p + 4);
    #pragma unroll
    for (int j = 0; j < 4; j++){ vv[j] = v0[j]; vv[4 + j] = v1[j]; }
  }
  #pragma unroll
  for (int j = 0; j < 8; j++){
    float v = vv[j] * sc + sh;
    if (SILU) v = v / (1.f + __expf(-v));
    tr[(t8 + j) * 40 + c] = f2bf(v);
  }
  __syncthreads();
  int t = tid >> 2, c8 = (tid & 3) * 8;
  us8 d = *(const us8*)&tr[t * 40 + c8];
  size_t row = OUTPAD ? ((size_t)b * 1026 + 1 + t0 + t) : ((size_t)b * 1024 + t0 + t);
  *(us8*)&out[row * 1024 + g * 32 + c8] = d;
}

// ---------------- GN2 apply (reduce partials inline) ----------------
template<int SILU>
__global__ __launch_bounds__(256) void gn2_apply(const unsigned short* __restrict__ c1,
    const float2* __restrict__ part2, const float* __restrict__ gma, const float* __restrict__ bta,
    unsigned short* __restrict__ outp)   // padded T-major out
{
  const int tid = threadIdx.x;
  const int ck = blockIdx.x & 31, b = blockIdx.x >> 5;
  const int g = tid >> 3;
  float S = 0.f, S2 = 0.f;
  #pragma unroll
  for (int tt = 0; tt < 8; tt++){
    float2 v = part2[(size_t)(b * 8 + tt) * 32 + g];
    S += v.x; S2 += v.y;
  }
  float mm = S * (1.f / 32768.f);
  float var = S2 * (1.f / 32768.f) - mm * mm;
  float2 s = make_float2(mm, rsqrtf(var + 1e-5f));
  float sc[4], sh[4];
  #pragma unroll
  for (int j = 0; j < 4; j++){ int ch = tid * 4 + j; sc[j] = gma[ch] * s.y; sh[j] = bta[ch] - s.x * sc[j]; }
  const unsigned short* p = c1 + ((size_t)b * 1024 + ck * 32) * 1024 + tid * 4;
  unsigned short* q = outp + ((size_t)b * 1026 + 1 + ck * 32) * 1024 + tid * 4;
  for (int r = 0; r < 32; r++){
    us4 v = *(const us4*)&p[(size_t)r * 1024];
    us4 o;
    #pragma unroll
    for (int j = 0; j < 4; j++){
      float f = bf2f(v[j]) * sc[j] + sh[j];
      if (SILU) f = f / (1.f + __expf(-f));
      o[j] = f2bf(f);
    }
    *(us4*)&q[(size_t)r * 1024] = o;
  }
}

// ---------------- GN8 apply (reduce partials inline) + GN32 partial emission ----------------
__global__ __launch_bounds__(256) void gn8_apply(const unsigned short* __restrict__ r,
    const float2* __restrict__ part8, const float* __restrict__ gma, const float* __restrict__ bta,
    unsigned short* __restrict__ xin, float2* __restrict__ part32){
  const int gid = blockIdx.x; const int tid = threadIdx.x;
  const int sub = gid & 15, g = (gid >> 4) & 7, b = gid >> 7;
  float S = 0.f, S2 = 0.f;
  #pragma unroll
  for (int tt = 0; tt < 8; tt++){
    float2 v = part8[(size_t)(b * 8 + tt) * 8 + g];
    S += v.x; S2 += v.y;
  }
  float mm = S * (1.f / 131072.f);
  float var = S2 * (1.f / 131072.f) - mm * mm;
  float2 s = make_float2(mm, rsqrtf(var + 1e-5f));
  const unsigned short* pr = r + ((size_t)(b * 8 + g)) * 131072 + sub * 8192;
  unsigned short* px = xin + ((size_t)(b * 8 + g)) * 131072 + sub * 8192;
  float ps = 0.f, ps2 = 0.f;
  for (int i = tid * 8; i < 8192; i += 2048){
    int c = g * 128 + sub * 8 + (i >> 10);
    float sc = gma[c] * s.y, sh = bta[c] - s.x * sc;
    us8 v = *(const us8*)&pr[i];
    us8 o;
    #pragma unroll
    for (int j = 0; j < 8; j++){
      float f = bf2f(v[j]) * sc + sh;
      ps += f; ps2 += f * f;
      o[j] = f2bf(f);
    }
    *(us8*)&px[i] = o;
  }
  ps = wredsum(ps); ps2 = wredsum(ps2);
  __shared__ float rs[4], rs2[4];
  if ((tid & 63) == 0){ rs[tid >> 6] = ps; rs2[tid >> 6] = ps2; }
  __syncthreads();
  if (tid == 0)
    part32[(size_t)(b * 8 + g) * 16 + sub] =
      make_float2(rs[0] + rs[1] + rs[2] + rs[3], rs2[0] + rs2[1] + rs2[2] + rs2[3]);
}

// ---------------- MFMA GEMM, counted-vmcnt double-buffered K-loop ----------------
template<int KK, int EPI, int GPART>
__global__ __launch_bounds__(256, 2) void gemm_k(
    const unsigned short* __restrict__ inT,
    const unsigned short* __restrict__ W,
    const float* __restrict__ bias,
    void* __restrict__ outp,
    void* __restrict__ resp,
    float2* __restrict__ part,
    int OC, int NT)
{
  __shared__ __align__(16) unsigned short Alds[2][128 * 64];
  __shared__ __align__(16) unsigned short Blds[2][128 * 64];
  __shared__ float sred[16];
  const int tid = threadIdx.x;
  const int lane = tid & 63;
  const int w = tid >> 6;
  const int wn = w >> 1, wo = w & 1;
  const int nt = blockIdx.x % NT;
  const int ot = blockIdx.x / NT;
  const int b = nt >> 3;
  const int t0 = (nt & 7) * 128;
  const int ob = ot * 128;
  const int rowbase = (KK == 3) ? (b * 1026 + t0) : (b * 1024 + t0);
  const int NTI = KK * 16;

  f32x4 acc[4][4];
  #pragma unroll
  for (int m = 0; m < 4; m++)
    #pragma unroll
    for (int n = 0; n < 4; n++) acc[m][n] = 0.f;

  const int lrow = lane >> 3;
  const int lblk = lane & 7;

  auto stage = [&](int kt, int bufsel){
    int kk = kt >> 4;
    int i0 = (kt & 15) * 64;
    const unsigned short* Ab = inT + (size_t)(rowbase + kk) * 1024;
    const unsigned short* Bb = W + ((size_t)kk * OC + ob) * 1024;
    #pragma unroll
    for (int j = 0; j < 4; ++j){
      int chunk = w * 4 + j;
      int row = chunk * 8 + lrow;
      int gcol = (lblk ^ (row & 7)) * 8;
      gll16(Ab + (size_t)row * 1024 + i0 + gcol, &Alds[bufsel][chunk * 512]);
      gll16(Bb + (size_t)row * 1024 + i0 + gcol, &Blds[bufsel][chunk * 512]);
    }
  };

  stage(0, 0);
  stage(1, 1);
  asm volatile("s_waitcnt vmcnt(8)" ::: "memory");
  __builtin_amdgcn_sched_barrier(0);
  __builtin_amdgcn_s_barrier();
  __builtin_amdgcn_sched_barrier(0);

  #pragma unroll 2
  for (int kt = 0; kt < NTI; ++kt){
    const int cur = kt & 1;
    const unsigned short* Ab = &Alds[cur][0];
    const unsigned short* Bb = &Blds[cur][0];
    bf16x8 af[2][4], bfv[2][4];
    #pragma unroll
    for (int m = 0; m < 4; m++){
      int row = wn * 64 + m * 16 + (lane & 15);
      #pragma unroll
      for (int k2 = 0; k2 < 2; k2++){
        int blk = ((lane >> 4) + k2 * 4) ^ (row & 7);
        af[k2][m] = *(const bf16x8*)&Ab[row * 64 + blk * 8];
      }
    }
    #pragma unroll
    for (int n = 0; n < 4; n++){
      int row = wo * 64 + n * 16 + (lane & 15);
      #pragma unroll
      for (int k2 = 0; k2 < 2; k2++){
        int blk = ((lane >> 4) + k2 * 4) ^ (row & 7);
        bfv[k2][n] = *(const bf16x8*)&Bb[row * 64 + blk * 8];
      }
    }
    asm volatile("s_waitcnt lgkmcnt(0)" ::: "memory");
    __builtin_amdgcn_sched_barrier(0);
    __builtin_amdgcn_s_barrier();       // all waves done reading buf[cur]
    __builtin_amdgcn_sched_barrier(0);
    if (kt + 2 < NTI) stage(kt + 2, cur);   // overwrite buf[cur]; loads fly under MFMA
    __builtin_amdgcn_sched_barrier(0);
    __builtin_amdgcn_s_setprio(1);
    #pragma unroll
    for (int k2 = 0; k2 < 2; k2++)
      #pragma unroll
      for (int m = 0; m < 4; m++)
        #pragma unroll
        for (int n = 0; n < 4; n++)
          acc[m][n] = mfma16(af[k2][m], bfv[k2][n], acc[m][n]);
    __builtin_amdgcn_s_setprio(0);
    __builtin_amdgcn_sched_barrier(0);
    if (kt + 2 < NTI){ asm volatile("s_waitcnt vmcnt(8)" ::: "memory"); }
    else             { asm volatile("s_waitcnt vmcnt(0)" ::: "memory"); }
    __builtin_amdgcn_sched_barrier(0);
    __builtin_amdgcn_s_barrier();       // next iter may read buf[cur^1]
    __builtin_amdgcn_sched_barrier(0);
  }

  if (EPI == 0){
    unsigned short* out = (unsigned short*)outp;
    float ps[2] = {0.f, 0.f}, ps2[2] = {0.f, 0.f};
    #pragma unroll
    for (int m = 0; m < 4; m++){
      int tl = t0 + wn * 64 + m * 16 + ((lane >> 4) * 4);
      #pragma unroll
      for (int n = 0; n < 4; n++){
        int o = ob + wo * 64 + n * 16 + (lane & 15);
        float bz = bias[o];
        size_t base = ((size_t)b * 1024 + tl) * OC + o;
        #pragma unroll
        for (int r = 0; r < 4; r++){
          float v = acc[m][n][r] + bz;
          if (GPART == 2){ ps[n >> 1] += v; ps2[n >> 1] += v * v; }
          out[base + (size_t)r * OC] = f2bf(v);
        }
      }
    }
    if (GPART == 2){
      #pragma unroll
      for (int j = 0; j < 2; j++){ ps[j] = wredsum(ps[j]); ps2[j] = wredsum(ps2[j]); }
      if (lane == 0){
        sred[w * 4 + 0] = ps[0]; sred[w * 4 + 1] = ps2[0];
        sred[w * 4 + 2] = ps[1]; sred[w * 4 + 3] = ps2[1];
      }
      __syncthreads();
      if (tid < 4){
        int g = tid, woo = g >> 1, jj = g & 1;
        float S  = sred[woo * 4 + jj * 2 + 0] + sred[(woo + 2) * 4 + jj * 2 + 0];
        float S2 = sred[woo * 4 + jj * 2 + 1] + sred[(woo + 2) * 4 + jj * 2 + 1];
        part[(size_t)(b * 8 + (nt & 7)) * 32 + ot * 4 + g] = make_float2(S, S2);
      }
    }
  } else if (EPI == 3){
    unsigned short* qkT = (unsigned short*)outp;
    unsigned short* vT  = (unsigned short*)resp;
    #pragma unroll
    for (int m = 0; m < 4; m++){
      int tl = t0 + wn * 64 + m * 16 + ((lane >> 4) * 4);
      #pragma unroll
      for (int n = 0; n < 4; n++){
        int o0 = ob + wo * 64 + n * 16;       // 16-aligned, uniform block
        int h = o0 / 192;
        int rem0 = o0 - h * 192;
        int o = o0 + (lane & 15);
        float bz = bias[o];
        if (rem0 < 128){
          size_t base = ((size_t)b * 1024 + tl) * 2048 + h * 128 + rem0 + (lane & 15);
          #pragma unroll
          for (int r = 0; r < 4; r++)
            qkT[base + (size_t)r * 2048] = f2bf(acc[m][n][r] + bz);
        } else {
          int c = rem0 - 128 + (lane & 15);
          size_t base = (((size_t)(b * 16 + h)) * 64 + c) * 1024 + tl;
          us4 o4;
          #pragma unroll
          for (int r = 0; r < 4; r++) o4[r] = f2bf(acc[m][n][r] + bz);
          *(us4*)&vT[base] = o4;
        }
      }
    }
  } else if (EPI == 4){
    unsigned short* out = (unsigned short*)outp;
    const unsigned short* xr = (const unsigned short*)resp;
    float ps = 0.f, ps2 = 0.f;
    #pragma unroll
    for (int m = 0; m < 4; m++){
      int tl = t0 + wn * 64 + m * 16 + ((lane >> 4) * 4);
      #pragma unroll
      for (int n = 0; n < 4; n++){
        int o = ob + wo * 64 + n * 16 + (lane & 15);
        float bz = bias[o];
        size_t base = ((size_t)b * 1024 + o) * 1024 + tl;
        us4 xv = *(const us4*)&xr[base];
        us4 ov;
        #pragma unroll
        for (int r = 0; r < 4; r++){
          float v = bf2f(xv[r]) + acc[m][n][r] + bz;
          if (GPART == 8){ ps += v; ps2 += v * v; }
          ov[r] = f2bf(v);
        }
        *(us4*)&out[base] = ov;
      }
    }
    if (GPART == 8){
      ps = wredsum(ps); ps2 = wredsum(ps2);
      if (lane == 0){ sred[w * 2] = ps; sred[w * 2 + 1] = ps2; }
      __syncthreads();
      if (tid == 0){
        float S = sred[0] + sred[2] + sred[4] + sred[6];
        float S2 = sred[1] + sred[3] + sred[5] + sred[7];
        part[(size_t)(b * 8 + (nt & 7)) * 8 + ot] = make_float2(S, S2);
      }
    }
  } else {
    float* out = (float*)outp;
    #pragma unroll
    for (int m = 0; m < 4; m++){
      int tl = t0 + wn * 64 + m * 16 + ((lane >> 4) * 4);
      #pragma unroll
      for (int n = 0; n < 4; n++){
        int o = ob + wo * 64 + n * 16 + (lane & 15);
        float bz = bias[o];
        size_t base = ((size_t)b * 1024 + o) * 1024 + tl;
        const unsigned short* xr = (const unsigned short*)resp;
        us4 xv = *(const us4*)&xr[base];
        f32x4 v;
        v[0] = bf2f(xv[0]); v[1] = bf2f(xv[1]); v[2] = bf2f(xv[2]); v[3] = bf2f(xv[3]);
        #pragma unroll
        for (int r = 0; r < 4; r++) v[r] += acc[m][n][r] + bz;
        *(f32x4*)&out[base] = v;
      }
    }
  }
}

// ---------------- flash attention v11: per-(m,k2) P slices -> 37KB LDS, 4 blocks/CU ----------------
__global__ __launch_bounds__(256, 4) void attn_k11(
    const unsigned short* __restrict__ qkT,  // (B,T,2048): h*128 + [0..63]=q, [64..127]=k
    const unsigned short* __restrict__ vT,   // (B,16,64,1024) ch-major V
    const float* __restrict__ btab,          // (16, 2048), pre-scaled by 8*log2e
    unsigned short* __restrict__ aT)         // (B,T,1024)
{
  __shared__ __align__(16) unsigned short Kb[2][64 * 64];
  __shared__ __align__(16) unsigned short Vb[2][64 * 64];
  __shared__ __align__(16) unsigned short Pb[4][16 * 32];   // per-wave 1KB slice, reused per (m,k2)
  __shared__ __align__(16) float cblds[288];   // bias for n in [-144,143]
  const int tid = threadIdx.x, lane = tid & 63, w = tid >> 6;
  const int d0 = blockIdx.x;
  const int xcd = d0 & 7, slot = d0 >> 3;
  const int bh = xcd * 16 + (slot >> 3);
  const int qt = slot & 7;
  const int h = bh & 15, b = bh >> 4;
  const int q0b = qt * 128;
  const int q0 = q0b + w * 32;
  const unsigned short* qk = qkT + (size_t)b * 1024 * 2048 + h * 128;
  const unsigned short* vh = vT + ((size_t)(b * 16 + h)) * 64 * 1024;
  const int lc = lane & 15, lg = lane >> 4;

  const float bneg = btab[h * 2048 + 0];      // s > q side (n <= -50)
  const float bpos = btab[h * 2048 + 2046];   // s < q side (n >= 50)

  // compact bias slice: cblds[i] = bias(n = i - 144)
  if (tid < 288) cblds[tid] = btab[h * 2048 + 879 + tid];

  bf16x8 qf[2][2];
  #pragma unroll
  for (int m = 0; m < 2; m++){
    const unsigned short* qrow = qk + (size_t)(q0 + m * 16 + lc) * 2048;
    #pragma unroll
    for (int k2 = 0; k2 < 2; k2++)
      qf[m][k2] = *(const bf16x8*)&qrow[k2 * 32 + lg * 8];
  }
  bf16x8 onesf;
  {
    us8 u;
    #pragma unroll
    for (int j = 0; j < 8; j++) u[j] = 0x3F80;     // bf16 1.0
    onesf = *(bf16x8*)&u;
  }
  f32x4 oacc[2][4], lacc[2];
  #pragma unroll
  for (int m = 0; m < 2; m++){
    #pragma unroll
    for (int cb = 0; cb < 4; cb++) oacc[m][cb] = 0.f;
    lacc[m] = 0.f;
  }

  const int lr = lane >> 3, lb = lane & 7;
  const float qs = 0.18033688011112042f;   // 0.125 * log2(e)
  const int X = (lc & 3) << 3;             // P-slice swizzle (8-col granular)

  #pragma unroll
  for (int j = 0; j < 2; j++){
    int chunk = w * 2 + j;
    int row = chunk * 8 + lr;
    int gcol = (lb ^ (row & 7)) * 8;
    gll16(qk + 64 + (size_t)row * 2048 + gcol, &Kb[0][chunk * 512]);
    gll16(vh + (size_t)row * 1024 + gcol, &Vb[0][chunk * 512]);
  }
  __syncthreads();

  for (int t = 0; t < 16; ++t){
    const int cur = t & 1;
    const int st0 = t * 64;
    if (t < 15){
      int nst = st0 + 64;
      #pragma unroll
      for (int j = 0; j < 2; j++){
        int chunk = w * 2 + j;
        int row = chunk * 8 + lr;
        int gcol = (lb ^ (row & 7)) * 8;
        gll16(qk + 64 + (size_t)(nst + row) * 2048 + gcol, &Kb[cur ^ 1][chunk * 512]);
        gll16(vh + (size_t)row * 1024 + nst + gcol, &Vb[cur ^ 1][chunk * 512]);
      }
    }
    // swapped QK^T: lane holds q=lc (per m), s = sub*16 + lg*4 + r
    f32x4 sfr[2][4];
    #pragma unroll
    for (int m = 0; m < 2; m++)
      #pragma unroll
      for (int sub = 0; sub < 4; sub++) sfr[m][sub] = 0.f;
    __builtin_amdgcn_s_setprio(1);
    #pragma unroll
    for (int sub = 0; sub < 4; sub++){
      int row = sub * 16 + lc;
      #pragma unroll
      for (int k2 = 0; k2 < 2; k2++){
        int blk = (lg + k2 * 4) ^ (row & 7);
        bf16x8 bk = *(const bf16x8*)&Kb[cur][row * 64 + blk * 8];
        sfr[0][sub] = mfma16(bk, qf[0][k2], sfr[0][sub]);
        sfr[1][sub] = mfma16(bk, qf[1][k2], sfr[1][sub]);
      }
    }
    __builtin_amdgcn_s_setprio(0);
    // fixed-shift softmax: P = exp2(s*qs + bias); bounded logits, no max tracking, no VALU sum
    const bool unineg = (st0 >= q0 + 81);        // all n = q-s <= -50
    const bool unipos = (st0 + 113 <= q0);       // all n >= 50
    if (unineg || unipos){
      const float bc = unineg ? bneg : bpos;
      #pragma unroll
      for (int m = 0; m < 2; m++)
        #pragma unroll
        for (int sub = 0; sub < 4; sub++)
          #pragma unroll
          for (int r = 0; r < 4; r++)
            sfr[m][sub][r] = exp2f(fmaf(sfr[m][sub][r], qs, bc));
    } else {
      #pragma unroll
      for (int m = 0; m < 2; m++){
        // i = n + 144 = (q_global - s_global) + 144
        const float* bp = &cblds[(q0 + m * 16 + lc) - st0 + 144 - lg * 4];
        #pragma unroll
        for (int sub = 0; sub < 4; sub++)
          #pragma unroll
          for (int r = 0; r < 4; r++)
            sfr[m][sub][r] = exp2f(fmaf(sfr[m][sub][r], qs, bp[-(sub * 16) - r]));
      }
    }
    // PV + l accumulation, P round-trips through a per-wave 16x32 slice per (m,k2)
    unsigned short* P = &Pb[w][0];
    __builtin_amdgcn_s_setprio(1);
    #pragma unroll
    for (int k2 = 0; k2 < 2; k2++){
      bf16x8 pa[2];
      #pragma unroll
      for (int m = 0; m < 2; m++){
        // write this (m,k2) slice: subs {2k2, 2k2+1} -> cols 0..31
        #pragma unroll
        for (int subp = 0; subp < 2; subp++){
          int sub = 2 * k2 + subp;
          int scol0 = subp * 16 + lg * 4;
          unsigned w0, w1;
          asm("v_cvt_pk_bf16_f32 %0, %1, %2" : "=v"(w0) : "v"(sfr[m][sub][0]), "v"(sfr[m][sub][1]));
          asm("v_cvt_pk_bf16_f32 %0, %1, %2" : "=v"(w1) : "v"(sfr[m][sub][2]), "v"(sfr[m][sub][3]));
          uint2 pk; pk.x = w0; pk.y = w1;
          *(uint2*)&P[lc * 32 + (scol0 ^ X)] = pk;
        }
        // read own A-fragment (DS pipe is in-order per wave; compiler inserts lgkmcnt)
        pa[m] = *(const bf16x8*)&P[lc * 32 + ((lg * 8) ^ X)];
      }
      #pragma unroll
      for (int cb = 0; cb < 4; cb++){
        int ch = cb * 16 + lc;
        int blkv = (lg + k2 * 4) ^ (ch & 7);
        bf16x8 bv = *(const bf16x8*)&Vb[cur][ch * 64 + blkv * 8];
        oacc[0][cb] = mfma16(pa[0], bv, oacc[0][cb]);
        oacc[1][cb] = mfma16(pa[1], bv, oacc[1][cb]);
      }
      lacc[0] = mfma16(pa[0], onesf, lacc[0]);
      lacc[1] = mfma16(pa[1], onesf, lacc[1]);
    }
    __builtin_amdgcn_s_setprio(0);
    __syncthreads();   // staged tile t+1 ready + buffer-reuse safety
  }
  #pragma unroll
  for (int m = 0; m < 2; m++)
    #pragma unroll
    for (int r = 0; r < 4; r++){
      float li = 1.0f / lacc[m][r];
      int tq = q0 + m * 16 + lg * 4 + r;
      #pragma unroll
      for (int cb = 0; cb < 4; cb++){
        int ch = h * 64 + cb * 16 + lc;
        aT[((size_t)b * 1024 + tq) * 1024 + ch] = f2bf(oacc[m][cb][r] * li);
      }
    }
}

// ---------------- launch ----------------
extern "C" void kernel_launch(void* const* d_in, const int* in_sizes, int n_in,
                              void* d_out, int out_size, void* d_ws, size_t ws_size,
                              hipStream_t stream)
{
  const float* x       = (const float*)d_in[0];
  const float* gn1_g   = (const float*)d_in[1];
  const float* gn1_b   = (const float*)d_in[2];
  const float* conv1_w = (const float*)d_in[3];
  const float* conv1_b = (const float*)d_in[4];
  const float* gn2_g   = (const float*)d_in[5];
  const float* gn2_b   = (const float*)d_in[6];
  const float* conv2_w = (const float*)d_in[7];
  const float* conv2_b = (const float*)d_in[8];
  const float* norm_g  = (const float*)d_in[9];
  const float* norm_b  = (const float*)d_in[10];
  const float* agn_g   = (const float*)d_in[11];
  const float* agn_b   = (const float*)d_in[12];
  const float* qkv_w   = (const float*)d_in[13];
  const float* qkv_b   = (const float*)d_in[14];
  const float* proj_w  = (const float*)d_in[15];
  const float* proj_b  = (const float*)d_in[16];
  const float* rel_emb = (const float*)d_in[17];

  if (ws_size < 139526144u) return;   // need ~133 MiB scratch

  char* ws = (char*)d_ws;
  unsigned short* w1p   = (unsigned short*)(ws + 0);
  unsigned short* w2p   = (unsigned short*)(ws + 6291456);
  unsigned short* wqkv  = (unsigned short*)(ws + 12582912);
  unsigned short* wproj = (unsigned short*)(ws + 18874368);
  float* btab           = (float*)(ws + 20971520);
  float2* stats1        = (float2*)(ws + 21102592);
  float2* part2n        = (float2*)(ws + 21110784);   // 2048 float2
  float2* part8n        = (float2*)(ws + 21127168);   // 512 float2
  float2* part32        = (float2*)(ws + 21131264);   // 1024 float2
  unsigned short* h1p   = (unsigned short*)(ws + 22020096);   // (B,1026,1024) bf16
  unsigned short* c1    = (unsigned short*)(ws + 38830080);   // (B,1024,1024) bf16
  unsigned short* g2p   = (unsigned short*)(ws + 55607296);   // (B,1026,1024) bf16
  unsigned short* qkT   = h1p;                                // reuse: (B,T,2048) bf16
  unsigned short* vT    = (unsigned short*)(ws + 55574528);   // (B,16,64,1024) bf16
  unsigned short* xb    = (unsigned short*)(ws + 72417280);   // (B,C,T) bf16; becomes x+h in-place
  unsigned short* attn_in = (unsigned short*)(ws + 72417280); // reuse after gn8 (xb dead)
  unsigned short* xin   = (unsigned short*)(ws + 105971712);  // (B,C,T) bf16 C-major
  unsigned short* aT    = (unsigned short*)(ws + 122748928);  // (B,T,C) bf16

  conv_w_prep2<<<8192, 256, 0, stream>>>(conv1_w, conv2_w, w1p, w2p);
  cast_f2b2<<<4096, 256, 0, stream>>>(qkv_w, proj_w, wqkv, wproj);
  misc_prep<<<192, 256, 0, stream>>>(h1p, g2p, rel_emb, btab);

  gn_stats_cast<<<256, 256, 0, stream>>>(x, stats1, xb);
  gn_apply_tr<1, 1, 1, 0><<<4096, 256, 0, stream>>>(xb, stats1, gn1_g, gn1_b, h1p);

  gemm_k<3, 0, 2><<<512, 256, 0, stream>>>(h1p, w1p, conv1_b, c1, nullptr, part2n, 1024, 64);
  gn2_apply<1><<<256, 256, 0, stream>>>(c1, part2n, gn2_g, gn2_b, g2p);

  // conv2 + residual, in-place on xb (bf16): xb <- conv2(g2p) + bias + xb, + GN8 partials
  gemm_k<3, 4, 8><<<512, 256, 0, stream>>>(g2p, w2p, conv2_b, xb, xb, part8n, 1024, 64);
  gn8_apply<<<1024, 256, 0, stream>>>(xb, part8n, norm_g, norm_b, xin, part32);

  gn_apply_tr<0, 1, 0, 1><<<4096, 256, 0, stream>>>(xin, part32, agn_g, agn_b, attn_in);

  gemm_k<1, 3, 0><<<1536, 256, 0, stream>>>(attn_in, wqkv, qkv_b, qkT, vT, nullptr, 3072, 64);

  attn_k11<<<1024, 256, 0, stream>>>(qkT, vT, btab, aT);

  gemm_k<1, 2, 0><<<512, 256, 0, stream>>>(aT, wproj, proj_b, d_out, xin, nullptr, 1024, 64);
}

// Round 16
// 336.056 us; speedup vs baseline: 1.0558x; 1.0558x over previous
//
#include <hip/hip_runtime.h>

typedef __attribute__((ext_vector_type(4))) float f32x4;
typedef __attribute__((ext_vector_type(8))) __bf16 bf16x8;
typedef __attribute__((ext_vector_type(4))) unsigned short us4;
typedef __attribute__((ext_vector_type(8))) unsigned short us8;

#define DEVI static __device__ __forceinline__

DEVI unsigned short f2bf(float f){
  union { float f; unsigned u; } x; x.f = f;
  unsigned r = x.u + 0x7fffu + ((x.u >> 16) & 1u);
  return (unsigned short)(r >> 16);
}
DEVI float bf2f(unsigned short h){
  union { unsigned u; float f; } x; x.u = ((unsigned)h) << 16;
  return x.f;
}

typedef __attribute__((address_space(1))) unsigned int gu32;
typedef __attribute__((address_space(3))) unsigned int lu32;
DEVI void gll16(const void* g, void* l){
  __builtin_amdgcn_global_load_lds((gu32*)g, (lu32*)l, 16, 0, 0);
}

DEVI f32x4 mfma16(bf16x8 a, bf16x8 b, f32x4 c){
  return __builtin_amdgcn_mfma_f32_16x16x32_bf16(a, b, c, 0, 0, 0);
}

DEVI float wredsum(float v){
  #pragma unroll
  for (int m = 1; m < 64; m <<= 1) v += __shfl_xor(v, m);
  return v;
}

// ---------------- weight prep (merged) ----------------
__global__ __launch_bounds__(256) void conv_w_prep2(const float* __restrict__ w1,
                                                    const float* __restrict__ w2,
                                                    unsigned short* __restrict__ wp1,
                                                    unsigned short* __restrict__ wp2){
  int idx = blockIdx.x * 256 + threadIdx.x;            // over 2*C*C
  int sel = idx >> 20;
  int lo  = idx & 1048575;
  const float* p = (sel ? w2 : w1) + (size_t)lo * 3;
  unsigned short* wp = sel ? wp2 : wp1;
  wp[lo]           = f2bf(p[0]);
  wp[1048576 + lo] = f2bf(p[1]);
  wp[2097152 + lo] = f2bf(p[2]);
}

__global__ __launch_bounds__(256) void cast_f2b2(const float* __restrict__ qw,
                                                 const float* __restrict__ pw,
                                                 unsigned short* __restrict__ qo,
                                                 unsigned short* __restrict__ po){
  int idx = blockIdx.x * 256 + threadIdx.x;            // 1048576 quads
  const float* src; unsigned short* dst; int lo;
  if (idx < 786432){ src = qw; dst = qo; lo = idx; }
  else             { src = pw; dst = po; lo = idx - 786432; }
  f32x4 v = *(const f32x4*)&src[(size_t)lo * 4];
  us4 o;
  #pragma unroll
  for (int j = 0; j < 4; j++) o[j] = f2bf(v[j]);
  *(us4*)&dst[(size_t)lo * 4] = o;
}

// blocks 0..63: zero pads; blocks 64..191: btab (pre-scaled by 8*log2e)
__global__ __launch_bounds__(256) void misc_prep(unsigned short* __restrict__ h1p,
                                                 unsigned short* __restrict__ g2p,
                                                 const float* __restrict__ emb,
                                                 float* __restrict__ btab){
  int bid = blockIdx.x;
  if (bid < 64){
    int idx = bid * 256 + threadIdx.x;                 // 16384
    int b = idx >> 11, rr = (idx >> 10) & 1, c = idx & 1023;
    size_t off = ((size_t)b * 1026 + (rr ? 1025 : 0)) * 1024 + c;
    h1p[off] = 0; g2p[off] = 0;
  } else {
    int idx = (bid - 64) * 256 + threadIdx.x;
    if (idx >= 2047 * 16) return;
    int d = idx >> 4, h = idx & 15;
    int n0 = d - 1023;
    int ret = (n0 < 0) ? 16 : 0;
    int n = (n0 < 0) ? -n0 : n0;
    int bucket;
    if (n < 8) bucket = ret + n;
    else {
      float ratio = logf((float)n * 0.125f) / 2.0794415416798357f;
      int vl = 8 + (int)(ratio * 8.0f);
      bucket = ret + (vl < 15 ? vl : 15);
    }
    btab[h * 2048 + d] = emb[bucket * 16 + h] * 11.541560327111707f;
  }
}

// ---------------- GN1 stats on fp32 + cast x -> bf16 (xb) ----------------
__global__ __launch_bounds__(256) void gn_stats_cast(const float* __restrict__ in,
                                                     float2* __restrict__ st,
                                                     unsigned short* __restrict__ xb){
  const int g = blockIdx.x; const int tid = threadIdx.x;
  const float* p = in + (size_t)g * 32768;
  unsigned short* q = xb + (size_t)g * 32768;
  float s = 0.f, s2 = 0.f;
  for (int i = tid * 4; i < 32768; i += 1024){
    f32x4 v = *(const f32x4*)&p[i];
    us4 o;
    #pragma unroll
    for (int j = 0; j < 4; j++){ s += v[j]; s2 += v[j] * v[j]; o[j] = f2bf(v[j]); }
    *(us4*)&q[i] = o;
  }
  s = wredsum(s); s2 = wredsum(s2);
  __shared__ float rs[4], rs2[4];
  if ((tid & 63) == 0){ rs[tid >> 6] = s; rs2[tid >> 6] = s2; }
  __syncthreads();
  if (tid == 0){
    float S = rs[0] + rs[1] + rs[2] + rs[3];
    float S2 = rs2[0] + rs2[1] + rs2[2] + rs2[3];
    float m = S * (1.f / 32768.f);
    float var = S2 * (1.f / 32768.f) - m * m;
    st[g] = make_float2(m, rsqrtf(var + 1e-5f));
  }
}

// C-major input -> T-major bf16 output (transpose through LDS), optional SiLU, optional padded rows
// FROMPART==1: st points at GN32 partials emitted by gn8_apply (reduce 4 on the fly)
template<int SILU, int INBF16, int OUTPAD, int FROMPART>
__global__ __launch_bounds__(256) void gn_apply_tr(
    const void* __restrict__ inp, const float2* __restrict__ st,
    const float* __restrict__ gma, const float* __restrict__ bta,
    unsigned short* __restrict__ out)
{
  const int gid = blockIdx.x;                 // b(3b) g(5b) tc(4b)
  const int tc = gid & 15, g = (gid >> 4) & 31, b = gid >> 9;
  const int tid = threadIdx.x;
  const int t0 = tc * 64;
  __shared__ __align__(16) unsigned short tr[64 * 40];
  float2 s;
  if (FROMPART){
    int g8 = g >> 2, k = g & 3;
    float S = 0.f, S2 = 0.f;
    #pragma unroll
    for (int j = 0; j < 4; j++){
      float2 v = st[(size_t)(b * 8 + g8) * 16 + k * 4 + j];
      S += v.x; S2 += v.y;
    }
    float m = S * (1.f / 32768.f);
    float var = S2 * (1.f / 32768.f) - m * m;
    s = make_float2(m, rsqrtf(var + 1e-5f));
  } else {
    s = st[b * 32 + g];
  }
  int c = tid >> 3, t8 = (tid & 7) * 8;
  int ch = g * 32 + c;
  float sc = gma[ch] * s.y;
  float sh = bta[ch] - s.x * sc;
  float vv[8];
  if (INBF16){
    const unsigned short* p = (const unsigned short*)inp + ((size_t)b * 1024 + ch) * 1024 + t0 + t8;
    us8 v = *(const us8*)p;
    #pragma unroll
    for (int j = 0; j < 8; j++) vv[j] = bf2f(v[j]);
  } else {
    const float* p = (const float*)inp + ((size_t)b * 1024 + ch) * 1024 + t0 + t8;
    f32x4 v0 = *(const f32x4*)p; f32x4 v1 = *(const f32x4*)(p + 4);
    #pragma unroll
    for (int j = 0; j < 4; j++){ vv[j] = v0[j]; vv[4 + j] = v1[j]; }
  }
  #pragma unroll
  for (int j = 0; j < 8; j++){
    float v = vv[j] * sc + sh;
    if (SILU) v = v / (1.f + __expf(-v));
    tr[(t8 + j) * 40 + c] = f2bf(v);
  }
  __syncthreads();
  int t = tid >> 2, c8 = (tid & 3) * 8;
  us8 d = *(const us8*)&tr[t * 40 + c8];
  size_t row = OUTPAD ? ((size_t)b * 1026 + 1 + t0 + t) : ((size_t)b * 1024 + t0 + t);
  *(us8*)&out[row * 1024 + g * 32 + c8] = d;
}

// ---------------- GN2 apply (reduce partials inline) ----------------
template<int SILU>
__global__ __launch_bounds__(256) void gn2_apply(const unsigned short* __restrict__ c1,
    const float2* __restrict__ part2, const float* __restrict__ gma, const float* __restrict__ bta,
    unsigned short* __restrict__ outp)   // padded T-major out
{
  const int tid = threadIdx.x;
  const int ck = blockIdx.x & 31, b = blockIdx.x >> 5;
  const int g = tid >> 3;
  float S = 0.f, S2 = 0.f;
  #pragma unroll
  for (int tt = 0; tt < 8; tt++){
    float2 v = part2[(size_t)(b * 8 + tt) * 32 + g];
    S += v.x; S2 += v.y;
  }
  float mm = S * (1.f / 32768.f);
  float var = S2 * (1.f / 32768.f) - mm * mm;
  float2 s = make_float2(mm, rsqrtf(var + 1e-5f));
  float sc[4], sh[4];
  #pragma unroll
  for (int j = 0; j < 4; j++){ int ch = tid * 4 + j; sc[j] = gma[ch] * s.y; sh[j] = bta[ch] - s.x * sc[j]; }
  const unsigned short* p = c1 + ((size_t)b * 1024 + ck * 32) * 1024 + tid * 4;
  unsigned short* q = outp + ((size_t)b * 1026 + 1 + ck * 32) * 1024 + tid * 4;
  for (int r = 0; r < 32; r++){
    us4 v = *(const us4*)&p[(size_t)r * 1024];
    us4 o;
    #pragma unroll
    for (int j = 0; j < 4; j++){
      float f = bf2f(v[j]) * sc[j] + sh[j];
      if (SILU) f = f / (1.f + __expf(-f));
      o[j] = f2bf(f);
    }
    *(us4*)&q[(size_t)r * 1024] = o;
  }
}

// ---------------- GN8 apply (reduce partials inline) + GN32 partial emission ----------------
__global__ __launch_bounds__(256) void gn8_apply(const unsigned short* __restrict__ r,
    const float2* __restrict__ part8, const float* __restrict__ gma, const float* __restrict__ bta,
    unsigned short* __restrict__ xin, float2* __restrict__ part32){
  const int gid = blockIdx.x; const int tid = threadIdx.x;
  const int sub = gid & 15, g = (gid >> 4) & 7, b = gid >> 7;
  float S = 0.f, S2 = 0.f;
  #pragma unroll
  for (int tt = 0; tt < 8; tt++){
    float2 v = part8[(size_t)(b * 8 + tt) * 8 + g];
    S += v.x; S2 += v.y;
  }
  float mm = S * (1.f / 131072.f);
  float var = S2 * (1.f / 131072.f) - mm * mm;
  float2 s = make_float2(mm, rsqrtf(var + 1e-5f));
  const unsigned short* pr = r + ((size_t)(b * 8 + g)) * 131072 + sub * 8192;
  unsigned short* px = xin + ((size_t)(b * 8 + g)) * 131072 + sub * 8192;
  float ps = 0.f, ps2 = 0.f;
  for (int i = tid * 8; i < 8192; i += 2048){
    int c = g * 128 + sub * 8 + (i >> 10);
    float sc = gma[c] * s.y, sh = bta[c] - s.x * sc;
    us8 v = *(const us8*)&pr[i];
    us8 o;
    #pragma unroll
    for (int j = 0; j < 8; j++){
      float f = bf2f(v[j]) * sc + sh;
      ps += f; ps2 += f * f;
      o[j] = f2bf(f);
    }
    *(us8*)&px[i] = o;
  }
  ps = wredsum(ps); ps2 = wredsum(ps2);
  __shared__ float rs[4], rs2[4];
  if ((tid & 63) == 0){ rs[tid >> 6] = ps; rs2[tid >> 6] = ps2; }
  __syncthreads();
  if (tid == 0)
    part32[(size_t)(b * 8 + g) * 16 + sub] =
      make_float2(rs[0] + rs[1] + rs[2] + rs[3], rs2[0] + rs2[1] + rs2[2] + rs2[3]);
}

// ---------------- MFMA GEMM, counted-vmcnt double-buffered K-loop ----------------
template<int KK, int EPI, int GPART>
__global__ __launch_bounds__(256, 2) void gemm_k(
    const unsigned short* __restrict__ inT,
    const unsigned short* __restrict__ W,
    const float* __restrict__ bias,
    void* __restrict__ outp,
    void* __restrict__ resp,
    float2* __restrict__ part,
    int OC, int NT)
{
  __shared__ __align__(16) unsigned short Alds[2][128 * 64];
  __shared__ __align__(16) unsigned short Blds[2][128 * 64];
  __shared__ float sred[16];
  const int tid = threadIdx.x;
  const int lane = tid & 63;
  const int w = tid >> 6;
  const int wn = w >> 1, wo = w & 1;
  const int nt = blockIdx.x % NT;
  const int ot = blockIdx.x / NT;
  const int b = nt >> 3;
  const int t0 = (nt & 7) * 128;
  const int ob = ot * 128;
  const int rowbase = (KK == 3) ? (b * 1026 + t0) : (b * 1024 + t0);
  const int NTI = KK * 16;

  f32x4 acc[4][4];
  #pragma unroll
  for (int m = 0; m < 4; m++)
    #pragma unroll
    for (int n = 0; n < 4; n++) acc[m][n] = 0.f;

  const int lrow = lane >> 3;
  const int lblk = lane & 7;

  auto stage = [&](int kt, int bufsel){
    int kk = kt >> 4;
    int i0 = (kt & 15) * 64;
    const unsigned short* Ab = inT + (size_t)(rowbase + kk) * 1024;
    const unsigned short* Bb = W + ((size_t)kk * OC + ob) * 1024;
    #pragma unroll
    for (int j = 0; j < 4; ++j){
      int chunk = w * 4 + j;
      int row = chunk * 8 + lrow;
      int gcol = (lblk ^ (row & 7)) * 8;
      gll16(Ab + (size_t)row * 1024 + i0 + gcol, &Alds[bufsel][chunk * 512]);
      gll16(Bb + (size_t)row * 1024 + i0 + gcol, &Blds[bufsel][chunk * 512]);
    }
  };

  stage(0, 0);
  stage(1, 1);
  asm volatile("s_waitcnt vmcnt(8)" ::: "memory");
  __builtin_amdgcn_sched_barrier(0);
  __builtin_amdgcn_s_barrier();
  __builtin_amdgcn_sched_barrier(0);

  #pragma unroll 2
  for (int kt = 0; kt < NTI; ++kt){
    const int cur = kt & 1;
    const unsigned short* Ab = &Alds[cur][0];
    const unsigned short* Bb = &Blds[cur][0];
    bf16x8 af[2][4], bfv[2][4];
    #pragma unroll
    for (int m = 0; m < 4; m++){
      int row = wn * 64 + m * 16 + (lane & 15);
      #pragma unroll
      for (int k2 = 0; k2 < 2; k2++){
        int blk = ((lane >> 4) + k2 * 4) ^ (row & 7);
        af[k2][m] = *(const bf16x8*)&Ab[row * 64 + blk * 8];
      }
    }
    #pragma unroll
    for (int n = 0; n < 4; n++){
      int row = wo * 64 + n * 16 + (lane & 15);
      #pragma unroll
      for (int k2 = 0; k2 < 2; k2++){
        int blk = ((lane >> 4) + k2 * 4) ^ (row & 7);
        bfv[k2][n] = *(const bf16x8*)&Bb[row * 64 + blk * 8];
      }
    }
    asm volatile("s_waitcnt lgkmcnt(0)" ::: "memory");
    __builtin_amdgcn_sched_barrier(0);
    __builtin_amdgcn_s_barrier();       // all waves done reading buf[cur]
    __builtin_amdgcn_sched_barrier(0);
    if (kt + 2 < NTI) stage(kt + 2, cur);   // overwrite buf[cur]; loads fly under MFMA
    __builtin_amdgcn_sched_barrier(0);
    __builtin_amdgcn_s_setprio(1);
    #pragma unroll
    for (int k2 = 0; k2 < 2; k2++)
      #pragma unroll
      for (int m = 0; m < 4; m++)
        #pragma unroll
        for (int n = 0; n < 4; n++)
          acc[m][n] = mfma16(af[k2][m], bfv[k2][n], acc[m][n]);
    __builtin_amdgcn_s_setprio(0);
    __builtin_amdgcn_sched_barrier(0);
    if (kt + 2 < NTI){ asm volatile("s_waitcnt vmcnt(8)" ::: "memory"); }
    else             { asm volatile("s_waitcnt vmcnt(0)" ::: "memory"); }
    __builtin_amdgcn_sched_barrier(0);
    __builtin_amdgcn_s_barrier();       // next iter may read buf[cur^1]
    __builtin_amdgcn_sched_barrier(0);
  }

  if (EPI == 0){
    unsigned short* out = (unsigned short*)outp;
    float ps[2] = {0.f, 0.f}, ps2[2] = {0.f, 0.f};
    #pragma unroll
    for (int m = 0; m < 4; m++){
      int tl = t0 + wn * 64 + m * 16 + ((lane >> 4) * 4);
      #pragma unroll
      for (int n = 0; n < 4; n++){
        int o = ob + wo * 64 + n * 16 + (lane & 15);
        float bz = bias[o];
        size_t base = ((size_t)b * 1024 + tl) * OC + o;
        #pragma unroll
        for (int r = 0; r < 4; r++){
          float v = acc[m][n][r] + bz;
          if (GPART == 2){ ps[n >> 1] += v; ps2[n >> 1] += v * v; }
          out[base + (size_t)r * OC] = f2bf(v);
        }
      }
    }
    if (GPART == 2){
      #pragma unroll
      for (int j = 0; j < 2; j++){ ps[j] = wredsum(ps[j]); ps2[j] = wredsum(ps2[j]); }
      if (lane == 0){
        sred[w * 4 + 0] = ps[0]; sred[w * 4 + 1] = ps2[0];
        sred[w * 4 + 2] = ps[1]; sred[w * 4 + 3] = ps2[1];
      }
      __syncthreads();
      if (tid < 4){
        int g = tid, woo = g >> 1, jj = g & 1;
        float S  = sred[woo * 4 + jj * 2 + 0] + sred[(woo + 2) * 4 + jj * 2 + 0];
        float S2 = sred[woo * 4 + jj * 2 + 1] + sred[(woo + 2) * 4 + jj * 2 + 1];
        part[(size_t)(b * 8 + (nt & 7)) * 32 + ot * 4 + g] = make_float2(S, S2);
      }
    }
  } else if (EPI == 3){
    unsigned short* qkT = (unsigned short*)outp;
    unsigned short* vT  = (unsigned short*)resp;
    #pragma unroll
    for (int m = 0; m < 4; m++){
      int tl = t0 + wn * 64 + m * 16 + ((lane >> 4) * 4);
      #pragma unroll
      for (int n = 0; n < 4; n++){
        int o0 = ob + wo * 64 + n * 16;       // 16-aligned, uniform block
        int h = o0 / 192;
        int rem0 = o0 - h * 192;
        int o = o0 + (lane & 15);
        float bz = bias[o];
        if (rem0 < 128){
          size_t base = ((size_t)b * 1024 + tl) * 2048 + h * 128 + rem0 + (lane & 15);
          #pragma unroll
          for (int r = 0; r < 4; r++)
            qkT[base + (size_t)r * 2048] = f2bf(acc[m][n][r] + bz);
        } else {
          int c = rem0 - 128 + (lane & 15);
          size_t base = (((size_t)(b * 16 + h)) * 64 + c) * 1024 + tl;
          us4 o4;
          #pragma unroll
          for (int r = 0; r < 4; r++) o4[r] = f2bf(acc[m][n][r] + bz);
          *(us4*)&vT[base] = o4;
        }
      }
    }
  } else if (EPI == 4){
    unsigned short* out = (unsigned short*)outp;
    const unsigned short* xr = (const unsigned short*)resp;
    float ps = 0.f, ps2 = 0.f;
    #pragma unroll
    for (int m = 0; m < 4; m++){
      int tl = t0 + wn * 64 + m * 16 + ((lane >> 4) * 4);
      #pragma unroll
      for (int n = 0; n < 4; n++){
        int o = ob + wo * 64 + n * 16 + (lane & 15);
        float bz = bias[o];
        size_t base = ((size_t)b * 1024 + o) * 1024 + tl;
        us4 xv = *(const us4*)&xr[base];
        us4 ov;
        #pragma unroll
        for (int r = 0; r < 4; r++){
          float v = bf2f(xv[r]) + acc[m][n][r] + bz;
          if (GPART == 8){ ps += v; ps2 += v * v; }
          ov[r] = f2bf(v);
        }
        *(us4*)&out[base] = ov;
      }
    }
    if (GPART == 8){
      ps = wredsum(ps); ps2 = wredsum(ps2);
      if (lane == 0){ sred[w * 2] = ps; sred[w * 2 + 1] = ps2; }
      __syncthreads();
      if (tid == 0){
        float S = sred[0] + sred[2] + sred[4] + sred[6];
        float S2 = sred[1] + sred[3] + sred[5] + sred[7];
        part[(size_t)(b * 8 + (nt & 7)) * 8 + ot] = make_float2(S, S2);
      }
    }
  } else {
    float* out = (float*)outp;
    #pragma unroll
    for (int m = 0; m < 4; m++){
      int tl = t0 + wn * 64 + m * 16 + ((lane >> 4) * 4);
      #pragma unroll
      for (int n = 0; n < 4; n++){
        int o = ob + wo * 64 + n * 16 + (lane & 15);
        float bz = bias[o];
        size_t base = ((size_t)b * 1024 + o) * 1024 + tl;
        const unsigned short* xr = (const unsigned short*)resp;
        us4 xv = *(const us4*)&xr[base];
        f32x4 v;
        v[0] = bf2f(xv[0]); v[1] = bf2f(xv[1]); v[2] = bf2f(xv[2]); v[3] = bf2f(xv[3]);
        #pragma unroll
        for (int r = 0; r < 4; r++) v[r] += acc[m][n][r] + bz;
        *(f32x4*)&out[base] = v;
      }
    }
  }
}

// ---------------- flash attention v9: 128 q-rows, compact bias table, l via ones-MFMA ----------------
__global__ __launch_bounds__(256, 3) void attn_k9(
    const unsigned short* __restrict__ qkT,  // (B,T,2048): h*128 + [0..63]=q, [64..127]=k
    const unsigned short* __restrict__ vT,   // (B,16,64,1024) ch-major V
    const float* __restrict__ btab,          // (16, 2048), pre-scaled by 8*log2e
    unsigned short* __restrict__ aT)         // (B,T,1024)
{
  __shared__ __align__(16) unsigned short Kb[2][64 * 64];
  __shared__ __align__(16) unsigned short Vb[2][64 * 64];
  __shared__ __align__(16) unsigned short Pb[4][32 * 64];
  __shared__ __align__(16) float cblds[288];   // bias for n in [-144,143]
  const int tid = threadIdx.x, lane = tid & 63, w = tid >> 6;
  const int d0 = blockIdx.x;
  const int xcd = d0 & 7, slot = d0 >> 3;
  const int bh = xcd * 16 + (slot >> 3);
  const int qt = slot & 7;
  const int h = bh & 15, b = bh >> 4;
  const int q0b = qt * 128;
  const int q0 = q0b + w * 32;
  const unsigned short* qk = qkT + (size_t)b * 1024 * 2048 + h * 128;
  const unsigned short* vh = vT + ((size_t)(b * 16 + h)) * 64 * 1024;
  const int lc = lane & 15, lg = lane >> 4;

  const float bneg = btab[h * 2048 + 0];      // s > q side (n <= -50)
  const float bpos = btab[h * 2048 + 2046];   // s < q side (n >= 50)

  // compact bias slice: cblds[i] = bias(n = i - 144)
  if (tid < 288) cblds[tid] = btab[h * 2048 + 879 + tid];

  bf16x8 qf[2][2];
  #pragma unroll
  for (int m = 0; m < 2; m++){
    const unsigned short* qrow = qk + (size_t)(q0 + m * 16 + lc) * 2048;
    #pragma unroll
    for (int k2 = 0; k2 < 2; k2++)
      qf[m][k2] = *(const bf16x8*)&qrow[k2 * 32 + lg * 8];
  }
  bf16x8 onesf;
  {
    us8 u;
    #pragma unroll
    for (int j = 0; j < 8; j++) u[j] = 0x3F80;     // bf16 1.0
    onesf = *(bf16x8*)&u;
  }
  f32x4 oacc[2][4], lacc[2];
  #pragma unroll
  for (int m = 0; m < 2; m++){
    #pragma unroll
    for (int cb = 0; cb < 4; cb++) oacc[m][cb] = 0.f;
    lacc[m] = 0.f;
  }

  const int lr = lane >> 3, lb = lane & 7;
  const float qs = 0.18033688011112042f;   // 0.125 * log2(e)

  #pragma unroll
  for (int j = 0; j < 2; j++){
    int chunk = w * 2 + j;
    int row = chunk * 8 + lr;
    int gcol = (lb ^ (row & 7)) * 8;
    gll16(qk + 64 + (size_t)row * 2048 + gcol, &Kb[0][chunk * 512]);
    gll16(vh + (size_t)row * 1024 + gcol, &Vb[0][chunk * 512]);
  }
  __syncthreads();

  for (int t = 0; t < 16; ++t){
    const int cur = t & 1;
    const int st0 = t * 64;
    if (t < 15){
      int nst = st0 + 64;
      #pragma unroll
      for (int j = 0; j < 2; j++){
        int chunk = w * 2 + j;
        int row = chunk * 8 + lr;
        int gcol = (lb ^ (row & 7)) * 8;
        gll16(qk + 64 + (size_t)(nst + row) * 2048 + gcol, &Kb[cur ^ 1][chunk * 512]);
        gll16(vh + (size_t)row * 1024 + nst + gcol, &Vb[cur ^ 1][chunk * 512]);
      }
    }
    // swapped QK^T: lane holds q=lc (per m), s = sub*16 + lg*4 + r
    f32x4 sfr[2][4];
    #pragma unroll
    for (int m = 0; m < 2; m++)
      #pragma unroll
      for (int sub = 0; sub < 4; sub++) sfr[m][sub] = 0.f;
    __builtin_amdgcn_s_setprio(1);
    #pragma unroll
    for (int sub = 0; sub < 4; sub++){
      int row = sub * 16 + lc;
      #pragma unroll
      for (int k2 = 0; k2 < 2; k2++){
        int blk = (lg + k2 * 4) ^ (row & 7);
        bf16x8 bk = *(const bf16x8*)&Kb[cur][row * 64 + blk * 8];
        sfr[0][sub] = mfma16(bk, qf[0][k2], sfr[0][sub]);
        sfr[1][sub] = mfma16(bk, qf[1][k2], sfr[1][sub]);
      }
    }
    __builtin_amdgcn_s_setprio(0);
    // fixed-shift softmax: P = exp2(s*qs + bias); bounded logits, no max tracking, no VALU sum
    const bool unineg = (st0 >= q0 + 81);        // all n = q-s <= -50
    const bool unipos = (st0 + 113 <= q0);       // all n >= 50
    if (unineg || unipos){
      const float bc = unineg ? bneg : bpos;
      #pragma unroll
      for (int m = 0; m < 2; m++)
        #pragma unroll
        for (int sub = 0; sub < 4; sub++)
          #pragma unroll
          for (int r = 0; r < 4; r++)
            sfr[m][sub][r] = exp2f(fmaf(sfr[m][sub][r], qs, bc));
    } else {
      #pragma unroll
      for (int m = 0; m < 2; m++){
        // i = n + 144 = (q_global - s_global) + 144
        const float* bp = &cblds[(q0 + m * 16 + lc) - st0 + 144 - lg * 4];
        #pragma unroll
        for (int sub = 0; sub < 4; sub++)
          #pragma unroll
          for (int r = 0; r < 4; r++)
            sfr[m][sub][r] = exp2f(fmaf(sfr[m][sub][r], qs, bp[-(sub * 16) - r]));
      }
    }
    // P write: cvt_pk pairs + 8B stores, swizzled
    unsigned short* P = &Pb[w][0];
    #pragma unroll
    for (int m = 0; m < 2; m++){
      int qrow = m * 16 + lc;
      int rsw = (qrow & 7) << 3;
      #pragma unroll
      for (int sub = 0; sub < 4; sub++){
        int col = sub * 16 + lg * 4;
        unsigned w0, w1;
        asm("v_cvt_pk_bf16_f32 %0, %1, %2" : "=v"(w0) : "v"(sfr[m][sub][0]), "v"(sfr[m][sub][1]));
        asm("v_cvt_pk_bf16_f32 %0, %1, %2" : "=v"(w1) : "v"(sfr[m][sub][2]), "v"(sfr[m][sub][3]));
        uint2 pk; pk.x = w0; pk.y = w1;
        *(uint2*)&P[qrow * 64 + (col ^ rsw)] = pk;
      }
    }
    // PV + l accumulation (P · ones) via MFMA
    __builtin_amdgcn_s_setprio(1);
    #pragma unroll
    for (int k2 = 0; k2 < 2; k2++){
      bf16x8 pa[2];
      #pragma unroll
      for (int m = 0; m < 2; m++){
        int rowp = m * 16 + lc;
        int blkp = (lg + k2 * 4) ^ (rowp & 7);
        pa[m] = *(const bf16x8*)&P[rowp * 64 + blkp * 8];
      }
      #pragma unroll
      for (int cb = 0; cb < 4; cb++){
        int ch = cb * 16 + lc;
        int blkv = (lg + k2 * 4) ^ (ch & 7);
        bf16x8 bv = *(const bf16x8*)&Vb[cur][ch * 64 + blkv * 8];
        oacc[0][cb] = mfma16(pa[0], bv, oacc[0][cb]);
        oacc[1][cb] = mfma16(pa[1], bv, oacc[1][cb]);
      }
      lacc[0] = mfma16(pa[0], onesf, lacc[0]);
      lacc[1] = mfma16(pa[1], onesf, lacc[1]);
    }
    __builtin_amdgcn_s_setprio(0);
    __syncthreads();   // staged tile t+1 ready + buffer-reuse safety
  }
  #pragma unroll
  for (int m = 0; m < 2; m++)
    #pragma unroll
    for (int r = 0; r < 4; r++){
      float li = 1.0f / lacc[m][r];
      int tq = q0 + m * 16 + lg * 4 + r;
      #pragma unroll
      for (int cb = 0; cb < 4; cb++){
        int ch = h * 64 + cb * 16 + lc;
        aT[((size_t)b * 1024 + tq) * 1024 + ch] = f2bf(oacc[m][cb][r] * li);
      }
    }
}

// ---------------- launch ----------------
extern "C" void kernel_launch(void* const* d_in, const int* in_sizes, int n_in,
                              void* d_out, int out_size, void* d_ws, size_t ws_size,
                              hipStream_t stream)
{
  const float* x       = (const float*)d_in[0];
  const float* gn1_g   = (const float*)d_in[1];
  const float* gn1_b   = (const float*)d_in[2];
  const float* conv1_w = (const float*)d_in[3];
  const float* conv1_b = (const float*)d_in[4];
  const float* gn2_g   = (const float*)d_in[5];
  const float* gn2_b   = (const float*)d_in[6];
  const float* conv2_w = (const float*)d_in[7];
  const float* conv2_b = (const float*)d_in[8];
  const float* norm_g  = (const float*)d_in[9];
  const float* norm_b  = (const float*)d_in[10];
  const float* agn_g   = (const float*)d_in[11];
  const float* agn_b   = (const float*)d_in[12];
  const float* qkv_w   = (const float*)d_in[13];
  const float* qkv_b   = (const float*)d_in[14];
  const float* proj_w  = (const float*)d_in[15];
  const float* proj_b  = (const float*)d_in[16];
  const float* rel_emb = (const float*)d_in[17];

  if (ws_size < 139526144u) return;   // need ~133 MiB scratch

  char* ws = (char*)d_ws;
  unsigned short* w1p   = (unsigned short*)(ws + 0);
  unsigned short* w2p   = (unsigned short*)(ws + 6291456);
  unsigned short* wqkv  = (unsigned short*)(ws + 12582912);
  unsigned short* wproj = (unsigned short*)(ws + 18874368);
  float* btab           = (float*)(ws + 20971520);
  float2* stats1        = (float2*)(ws + 21102592);
  float2* part2n        = (float2*)(ws + 21110784);   // 2048 float2
  float2* part8n        = (float2*)(ws + 21127168);   // 512 float2
  float2* part32        = (float2*)(ws + 21131264);   // 1024 float2
  unsigned short* h1p   = (unsigned short*)(ws + 22020096);   // (B,1026,1024) bf16
  unsigned short* c1    = (unsigned short*)(ws + 38830080);   // (B,1024,1024) bf16
  unsigned short* g2p   = (unsigned short*)(ws + 55607296);   // (B,1026,1024) bf16
  unsigned short* qkT   = h1p;                                // reuse: (B,T,2048) bf16
  unsigned short* vT    = (unsigned short*)(ws + 55574528);   // (B,16,64,1024) bf16
  unsigned short* xb    = (unsigned short*)(ws + 72417280);   // (B,C,T) bf16; becomes x+h in-place
  unsigned short* attn_in = (unsigned short*)(ws + 72417280); // reuse after gn8 (xb dead)
  unsigned short* xin   = (unsigned short*)(ws + 105971712);  // (B,C,T) bf16 C-major
  unsigned short* aT    = (unsigned short*)(ws + 122748928);  // (B,T,C) bf16

  conv_w_prep2<<<8192, 256, 0, stream>>>(conv1_w, conv2_w, w1p, w2p);
  cast_f2b2<<<4096, 256, 0, stream>>>(qkv_w, proj_w, wqkv, wproj);
  misc_prep<<<192, 256, 0, stream>>>(h1p, g2p, rel_emb, btab);

  gn_stats_cast<<<256, 256, 0, stream>>>(x, stats1, xb);
  gn_apply_tr<1, 1, 1, 0><<<4096, 256, 0, stream>>>(xb, stats1, gn1_g, gn1_b, h1p);

  gemm_k<3, 0, 2><<<512, 256, 0, stream>>>(h1p, w1p, conv1_b, c1, nullptr, part2n, 1024, 64);
  gn2_apply<1><<<256, 256, 0, stream>>>(c1, part2n, gn2_g, gn2_b, g2p);

  // conv2 + residual, in-place on xb (bf16): xb <- conv2(g2p) + bias + xb, + GN8 partials
  gemm_k<3, 4, 8><<<512, 256, 0, stream>>>(g2p, w2p, conv2_b, xb, xb, part8n, 1024, 64);
  gn8_apply<<<1024, 256, 0, stream>>>(xb, part8n, norm_g, norm_b, xin, part32);

  gn_apply_tr<0, 1, 0, 1><<<4096, 256, 0, stream>>>(xin, part32, agn_g, agn_b, attn_in);

  gemm_k<1, 3, 0><<<1536, 256, 0, stream>>>(attn_in, wqkv, qkv_b, qkT, vT, nullptr, 3072, 64);

  attn_k9<<<1024, 256, 0, stream>>>(qkT, vT, btab, aT);

  gemm_k<1, 2, 0><<<512, 256, 0, stream>>>(aT, wproj, proj_b, d_out, xin, nullptr, 1024, 64);
}

// Round 17
// 334.067 us; speedup vs baseline: 1.0621x; 1.0060x over previous
//
#include <hip/hip_runtime.h>

typedef __attribute__((ext_vector_type(4))) float f32x4;
typedef __attribute__((ext_vector_type(8))) __bf16 bf16x8;
typedef __attribute__((ext_vector_type(4))) unsigned short us4;
typedef __attribute__((ext_vector_type(8))) unsigned short us8;

#define DEVI static __device__ __forceinline__

DEVI unsigned short f2bf(float f){
  union { float f; unsigned u; } x; x.f = f;
  unsigned r = x.u + 0x7fffu + ((x.u >> 16) & 1u);
  return (unsigned short)(r >> 16);
}
DEVI float bf2f(unsigned short h){
  union { unsigned u; float f; } x; x.u = ((unsigned)h) << 16;
  return x.f;
}

typedef __attribute__((address_space(1))) unsigned int gu32;
typedef __attribute__((address_space(3))) unsigned int lu32;
DEVI void gll16(const void* g, void* l){
  __builtin_amdgcn_global_load_lds((gu32*)g, (lu32*)l, 16, 0, 0);
}

DEVI f32x4 mfma16(bf16x8 a, bf16x8 b, f32x4 c){
  return __builtin_amdgcn_mfma_f32_16x16x32_bf16(a, b, c, 0, 0, 0);
}

DEVI float wredsum(float v){
  #pragma unroll
  for (int m = 1; m < 64; m <<= 1) v += __shfl_xor(v, m);
  return v;
}

// ---------------- merged prep: weights cast + pads + btab + GN1 stats/cast ----------------
// blocks [0,8192): conv w1/w2 -> bf16 (K-major split)
// blocks [8192,12288): qkv/proj w -> bf16
// blocks [12288,12352): zero pads
// blocks [12352,12480): btab (pre-scaled by 8*log2e)
// blocks [12480,12736): GN1 stats on fp32 x + cast x -> bf16 xb
__global__ __launch_bounds__(256) void prep_all(
    const float* __restrict__ w1, const float* __restrict__ w2,
    unsigned short* __restrict__ wp1, unsigned short* __restrict__ wp2,
    const float* __restrict__ qw, const float* __restrict__ pw,
    unsigned short* __restrict__ qo, unsigned short* __restrict__ po,
    unsigned short* __restrict__ h1p, unsigned short* __restrict__ g2p,
    const float* __restrict__ emb, float* __restrict__ btab,
    const float* __restrict__ x, float2* __restrict__ st,
    unsigned short* __restrict__ xb)
{
  const int bid = blockIdx.x;
  const int tid = threadIdx.x;
  if (bid < 8192){
    int idx = bid * 256 + tid;                         // over 2*C*C
    int sel = idx >> 20;
    int lo  = idx & 1048575;
    const float* p = (sel ? w2 : w1) + (size_t)lo * 3;
    unsigned short* wp = sel ? wp2 : wp1;
    wp[lo]           = f2bf(p[0]);
    wp[1048576 + lo] = f2bf(p[1]);
    wp[2097152 + lo] = f2bf(p[2]);
  } else if (bid < 12288){
    int idx = (bid - 8192) * 256 + tid;                // 1048576 quads
    const float* src; unsigned short* dst; int lo;
    if (idx < 786432){ src = qw; dst = qo; lo = idx; }
    else             { src = pw; dst = po; lo = idx - 786432; }
    f32x4 v = *(const f32x4*)&src[(size_t)lo * 4];
    us4 o;
    #pragma unroll
    for (int j = 0; j < 4; j++) o[j] = f2bf(v[j]);
    *(us4*)&dst[(size_t)lo * 4] = o;
  } else if (bid < 12352){
    int idx = (bid - 12288) * 256 + tid;               // 16384
    int b = idx >> 11, rr = (idx >> 10) & 1, c = idx & 1023;
    size_t off = ((size_t)b * 1026 + (rr ? 1025 : 0)) * 1024 + c;
    h1p[off] = 0; g2p[off] = 0;
  } else if (bid < 12480){
    int idx = (bid - 12352) * 256 + tid;
    if (idx >= 2047 * 16) return;
    int d = idx >> 4, h = idx & 15;
    int n0 = d - 1023;
    int ret = (n0 < 0) ? 16 : 0;
    int n = (n0 < 0) ? -n0 : n0;
    int bucket;
    if (n < 8) bucket = ret + n;
    else {
      float ratio = logf((float)n * 0.125f) / 2.0794415416798357f;
      int vl = 8 + (int)(ratio * 8.0f);
      bucket = ret + (vl < 15 ? vl : 15);
    }
    btab[h * 2048 + d] = emb[bucket * 16 + h] * 11.541560327111707f;
  } else {
    const int g = bid - 12480;                         // 256 groups
    const float* p = x + (size_t)g * 32768;
    unsigned short* q = xb + (size_t)g * 32768;
    float s = 0.f, s2 = 0.f;
    for (int i = tid * 4; i < 32768; i += 1024){
      f32x4 v = *(const f32x4*)&p[i];
      us4 o;
      #pragma unroll
      for (int j = 0; j < 4; j++){ s += v[j]; s2 += v[j] * v[j]; o[j] = f2bf(v[j]); }
      *(us4*)&q[i] = o;
    }
    s = wredsum(s); s2 = wredsum(s2);
    __shared__ float rs[4], rs2[4];
    if ((tid & 63) == 0){ rs[tid >> 6] = s; rs2[tid >> 6] = s2; }
    __syncthreads();
    if (tid == 0){
      float S = rs[0] + rs[1] + rs[2] + rs[3];
      float S2 = rs2[0] + rs2[1] + rs2[2] + rs2[3];
      float m = S * (1.f / 32768.f);
      float var = S2 * (1.f / 32768.f) - m * m;
      st[g] = make_float2(m, rsqrtf(var + 1e-5f));
    }
  }
}

// C-major input -> T-major bf16 output (transpose through LDS), optional SiLU, optional padded rows
// FROMPART==1: st points at GN32 partials emitted by gn8_apply (reduce 4 on the fly)
template<int SILU, int INBF16, int OUTPAD, int FROMPART>
__global__ __launch_bounds__(256) void gn_apply_tr(
    const void* __restrict__ inp, const float2* __restrict__ st,
    const float* __restrict__ gma, const float* __restrict__ bta,
    unsigned short* __restrict__ out)
{
  const int gid = blockIdx.x;                 // b(3b) g(5b) tc(4b)
  const int tc = gid & 15, g = (gid >> 4) & 31, b = gid >> 9;
  const int tid = threadIdx.x;
  const int t0 = tc * 64;
  __shared__ __align__(16) unsigned short tr[64 * 40];
  float2 s;
  if (FROMPART){
    int g8 = g >> 2, k = g & 3;
    float S = 0.f, S2 = 0.f;
    #pragma unroll
    for (int j = 0; j < 4; j++){
      float2 v = st[(size_t)(b * 8 + g8) * 16 + k * 4 + j];
      S += v.x; S2 += v.y;
    }
    float m = S * (1.f / 32768.f);
    float var = S2 * (1.f / 32768.f) - m * m;
    s = make_float2(m, rsqrtf(var + 1e-5f));
  } else {
    s = st[b * 32 + g];
  }
  int c = tid >> 3, t8 = (tid & 7) * 8;
  int ch = g * 32 + c;
  float sc = gma[ch] * s.y;
  float sh = bta[ch] - s.x * sc;
  float vv[8];
  if (INBF16){
    const unsigned short* p = (const unsigned short*)inp + ((size_t)b * 1024 + ch) * 1024 + t0 + t8;
    us8 v = *(const us8*)p;
    #pragma unroll
    for (int j = 0; j < 8; j++) vv[j] = bf2f(v[j]);
  } else {
    const float* p = (const float*)inp + ((size_t)b * 1024 + ch) * 1024 + t0 + t8;
    f32x4 v0 = *(const f32x4*)p; f32x4 v1 = *(const f32x4*)(p + 4);
    #pragma unroll
    for (int j = 0; j < 4; j++){ vv[j] = v0[j]; vv[4 + j] = v1[j]; }
  }
  #pragma unroll
  for (int j = 0; j < 8; j++){
    float v = vv[j] * sc + sh;
    if (SILU) v = v / (1.f + __expf(-v));
    tr[(t8 + j) * 40 + c] = f2bf(v);
  }
  __syncthreads();
  int t = tid >> 2, c8 = (tid & 3) * 8;
  us8 d = *(const us8*)&tr[t * 40 + c8];
  size_t row = OUTPAD ? ((size_t)b * 1026 + 1 + t0 + t) : ((size_t)b * 1024 + t0 + t);
  *(us8*)&out[row * 1024 + g * 32 + c8] = d;
}

// ---------------- GN2 apply (reduce partials inline) ----------------
template<int SILU>
__global__ __launch_bounds__(256) void gn2_apply(const unsigned short* __restrict__ c1,
    const float2* __restrict__ part2, const float* __restrict__ gma, const float* __restrict__ bta,
    unsigned short* __restrict__ outp)   // padded T-major out
{
  const int tid = threadIdx.x;
  const int ck = blockIdx.x & 31, b = blockIdx.x >> 5;
  const int g = tid >> 3;
  float S = 0.f, S2 = 0.f;
  #pragma unroll
  for (int tt = 0; tt < 8; tt++){
    float2 v = part2[(size_t)(b * 8 + tt) * 32 + g];
    S += v.x; S2 += v.y;
  }
  float mm = S * (1.f / 32768.f);
  float var = S2 * (1.f / 32768.f) - mm * mm;
  float2 s = make_float2(mm, rsqrtf(var + 1e-5f));
  float sc[4], sh[4];
  #pragma unroll
  for (int j = 0; j < 4; j++){ int ch = tid * 4 + j; sc[j] = gma[ch] * s.y; sh[j] = bta[ch] - s.x * sc[j]; }
  const unsigned short* p = c1 + ((size_t)b * 1024 + ck * 32) * 1024 + tid * 4;
  unsigned short* q = outp + ((size_t)b * 1026 + 1 + ck * 32) * 1024 + tid * 4;
  for (int r = 0; r < 32; r++){
    us4 v = *(const us4*)&p[(size_t)r * 1024];
    us4 o;
    #pragma unroll
    for (int j = 0; j < 4; j++){
      float f = bf2f(v[j]) * sc[j] + sh[j];
      if (SILU) f = f / (1.f + __expf(-f));
      o[j] = f2bf(f);
    }
    *(us4*)&q[(size_t)r * 1024] = o;
  }
}

// ---------------- GN8 apply (reduce partials inline) + GN32 partial emission ----------------
__global__ __launch_bounds__(256) void gn8_apply(const unsigned short* __restrict__ r,
    const float2* __restrict__ part8, const float* __restrict__ gma, const float* __restrict__ bta,
    unsigned short* __restrict__ xin, float2* __restrict__ part32){
  const int gid = blockIdx.x; const int tid = threadIdx.x;
  const int sub = gid & 15, g = (gid >> 4) & 7, b = gid >> 7;
  float S = 0.f, S2 = 0.f;
  #pragma unroll
  for (int tt = 0; tt < 8; tt++){
    float2 v = part8[(size_t)(b * 8 + tt) * 8 + g];
    S += v.x; S2 += v.y;
  }
  float mm = S * (1.f / 131072.f);
  float var = S2 * (1.f / 131072.f) - mm * mm;
  float2 s = make_float2(mm, rsqrtf(var + 1e-5f));
  const unsigned short* pr = r + ((size_t)(b * 8 + g)) * 131072 + sub * 8192;
  unsigned short* px = xin + ((size_t)(b * 8 + g)) * 131072 + sub * 8192;
  float ps = 0.f, ps2 = 0.f;
  for (int i = tid * 8; i < 8192; i += 2048){
    int c = g * 128 + sub * 8 + (i >> 10);
    float sc = gma[c] * s.y, sh = bta[c] - s.x * sc;
    us8 v = *(const us8*)&pr[i];
    us8 o;
    #pragma unroll
    for (int j = 0; j < 8; j++){
      float f = bf2f(v[j]) * sc + sh;
      ps += f; ps2 += f * f;
      o[j] = f2bf(f);
    }
    *(us8*)&px[i] = o;
  }
  ps = wredsum(ps); ps2 = wredsum(ps2);
  __shared__ float rs[4], rs2[4];
  if ((tid & 63) == 0){ rs[tid >> 6] = ps; rs2[tid >> 6] = ps2; }
  __syncthreads();
  if (tid == 0)
    part32[(size_t)(b * 8 + g) * 16 + sub] =
      make_float2(rs[0] + rs[1] + rs[2] + rs[3], rs2[0] + rs2[1] + rs2[2] + rs2[3]);
}

// ---------------- MFMA GEMM, counted-vmcnt double-buffered K-loop ----------------
template<int KK, int EPI, int GPART>
__global__ __launch_bounds__(256, 2) void gemm_k(
    const unsigned short* __restrict__ inT,
    const unsigned short* __restrict__ W,
    const float* __restrict__ bias,
    void* __restrict__ outp,
    void* __restrict__ resp,
    float2* __restrict__ part,
    int OC, int NT)
{
  __shared__ __align__(16) unsigned short Alds[2][128 * 64];
  __shared__ __align__(16) unsigned short Blds[2][128 * 64];
  __shared__ float sred[16];
  const int tid = threadIdx.x;
  const int lane = tid & 63;
  const int w = tid >> 6;
  const int wn = w >> 1, wo = w & 1;
  const int nt = blockIdx.x % NT;
  const int ot = blockIdx.x / NT;
  const int b = nt >> 3;
  const int t0 = (nt & 7) * 128;
  const int ob = ot * 128;
  const int rowbase = (KK == 3) ? (b * 1026 + t0) : (b * 1024 + t0);
  const int NTI = KK * 16;

  f32x4 acc[4][4];
  #pragma unroll
  for (int m = 0; m < 4; m++)
    #pragma unroll
    for (int n = 0; n < 4; n++) acc[m][n] = 0.f;

  const int lrow = lane >> 3;
  const int lblk = lane & 7;

  auto stage = [&](int kt, int bufsel){
    int kk = kt >> 4;
    int i0 = (kt & 15) * 64;
    const unsigned short* Ab = inT + (size_t)(rowbase + kk) * 1024;
    const unsigned short* Bb = W + ((size_t)kk * OC + ob) * 1024;
    #pragma unroll
    for (int j = 0; j < 4; ++j){
      int chunk = w * 4 + j;
      int row = chunk * 8 + lrow;
      int gcol = (lblk ^ (row & 7)) * 8;
      gll16(Ab + (size_t)row * 1024 + i0 + gcol, &Alds[bufsel][chunk * 512]);
      gll16(Bb + (size_t)row * 1024 + i0 + gcol, &Blds[bufsel][chunk * 512]);
    }
  };

  stage(0, 0);
  stage(1, 1);
  asm volatile("s_waitcnt vmcnt(8)" ::: "memory");
  __builtin_amdgcn_sched_barrier(0);
  __builtin_amdgcn_s_barrier();
  __builtin_amdgcn_sched_barrier(0);

  #pragma unroll 2
  for (int kt = 0; kt < NTI; ++kt){
    const int cur = kt & 1;
    const unsigned short* Ab = &Alds[cur][0];
    const unsigned short* Bb = &Blds[cur][0];
    bf16x8 af[2][4], bfv[2][4];
    #pragma unroll
    for (int m = 0; m < 4; m++){
      int row = wn * 64 + m * 16 + (lane & 15);
      #pragma unroll
      for (int k2 = 0; k2 < 2; k2++){
        int blk = ((lane >> 4) + k2 * 4) ^ (row & 7);
        af[k2][m] = *(const bf16x8*)&Ab[row * 64 + blk * 8];
      }
    }
    #pragma unroll
    for (int n = 0; n < 4; n++){
      int row = wo * 64 + n * 16 + (lane & 15);
      #pragma unroll
      for (int k2 = 0; k2 < 2; k2++){
        int blk = ((lane >> 4) + k2 * 4) ^ (row & 7);
        bfv[k2][n] = *(const bf16x8*)&Bb[row * 64 + blk * 8];
      }
    }
    asm volatile("s_waitcnt lgkmcnt(0)" ::: "memory");
    __builtin_amdgcn_sched_barrier(0);
    __builtin_amdgcn_s_barrier();       // all waves done reading buf[cur]
    __builtin_amdgcn_sched_barrier(0);
    if (kt + 2 < NTI) stage(kt + 2, cur);   // overwrite buf[cur]; loads fly under MFMA
    __builtin_amdgcn_sched_barrier(0);
    __builtin_amdgcn_s_setprio(1);
    #pragma unroll
    for (int k2 = 0; k2 < 2; k2++)
      #pragma unroll
      for (int m = 0; m < 4; m++)
        #pragma unroll
        for (int n = 0; n < 4; n++)
          acc[m][n] = mfma16(af[k2][m], bfv[k2][n], acc[m][n]);
    __builtin_amdgcn_s_setprio(0);
    __builtin_amdgcn_sched_barrier(0);
    if (kt + 2 < NTI){ asm volatile("s_waitcnt vmcnt(8)" ::: "memory"); }
    else             { asm volatile("s_waitcnt vmcnt(0)" ::: "memory"); }
    __builtin_amdgcn_sched_barrier(0);
    __builtin_amdgcn_s_barrier();       // next iter may read buf[cur^1]
    __builtin_amdgcn_sched_barrier(0);
  }

  if (EPI == 0){
    unsigned short* out = (unsigned short*)outp;
    float ps[2] = {0.f, 0.f}, ps2[2] = {0.f, 0.f};
    #pragma unroll
    for (int m = 0; m < 4; m++){
      int tl = t0 + wn * 64 + m * 16 + ((lane >> 4) * 4);
      #pragma unroll
      for (int n = 0; n < 4; n++){
        int o = ob + wo * 64 + n * 16 + (lane & 15);
        float bz = bias[o];
        size_t base = ((size_t)b * 1024 + tl) * OC + o;
        #pragma unroll
        for (int r = 0; r < 4; r++){
          float v = acc[m][n][r] + bz;
          if (GPART == 2){ ps[n >> 1] += v; ps2[n >> 1] += v * v; }
          out[base + (size_t)r * OC] = f2bf(v);
        }
      }
    }
    if (GPART == 2){
      #pragma unroll
      for (int j = 0; j < 2; j++){ ps[j] = wredsum(ps[j]); ps2[j] = wredsum(ps2[j]); }
      if (lane == 0){
        sred[w * 4 + 0] = ps[0]; sred[w * 4 + 1] = ps2[0];
        sred[w * 4 + 2] = ps[1]; sred[w * 4 + 3] = ps2[1];
      }
      __syncthreads();
      if (tid < 4){
        int g = tid, woo = g >> 1, jj = g & 1;
        float S  = sred[woo * 4 + jj * 2 + 0] + sred[(woo + 2) * 4 + jj * 2 + 0];
        float S2 = sred[woo * 4 + jj * 2 + 1] + sred[(woo + 2) * 4 + jj * 2 + 1];
        part[(size_t)(b * 8 + (nt & 7)) * 32 + ot * 4 + g] = make_float2(S, S2);
      }
    }
  } else if (EPI == 3){
    unsigned short* qkT = (unsigned short*)outp;
    unsigned short* vT  = (unsigned short*)resp;
    #pragma unroll
    for (int m = 0; m < 4; m++){
      int tl = t0 + wn * 64 + m * 16 + ((lane >> 4) * 4);
      #pragma unroll
      for (int n = 0; n < 4; n++){
        int o0 = ob + wo * 64 + n * 16;       // 16-aligned, uniform block
        int h = o0 / 192;
        int rem0 = o0 - h * 192;
        int o = o0 + (lane & 15);
        float bz = bias[o];
        if (rem0 < 128){
          size_t base = ((size_t)b * 1024 + tl) * 2048 + h * 128 + rem0 + (lane & 15);
          #pragma unroll
          for (int r = 0; r < 4; r++)
            qkT[base + (size_t)r * 2048] = f2bf(acc[m][n][r] + bz);
        } else {
          int c = rem0 - 128 + (lane & 15);
          size_t base = (((size_t)(b * 16 + h)) * 64 + c) * 1024 + tl;
          us4 o4;
          #pragma unroll
          for (int r = 0; r < 4; r++) o4[r] = f2bf(acc[m][n][r] + bz);
          *(us4*)&vT[base] = o4;
        }
      }
    }
  } else if (EPI == 4){
    unsigned short* out = (unsigned short*)outp;
    const unsigned short* xr = (const unsigned short*)resp;
    float ps = 0.f, ps2 = 0.f;
    #pragma unroll
    for (int m = 0; m < 4; m++){
      int tl = t0 + wn * 64 + m * 16 + ((lane >> 4) * 4);
      #pragma unroll
      for (int n = 0; n < 4; n++){
        int o = ob + wo * 64 + n * 16 + (lane & 15);
        float bz = bias[o];
        size_t base = ((size_t)b * 1024 + o) * 1024 + tl;
        us4 xv = *(const us4*)&xr[base];
        us4 ov;
        #pragma unroll
        for (int r = 0; r < 4; r++){
          float v = bf2f(xv[r]) + acc[m][n][r] + bz;
          if (GPART == 8){ ps += v; ps2 += v * v; }
          ov[r] = f2bf(v);
        }
        *(us4*)&out[base] = ov;
      }
    }
    if (GPART == 8){
      ps = wredsum(ps); ps2 = wredsum(ps2);
      if (lane == 0){ sred[w * 2] = ps; sred[w * 2 + 1] = ps2; }
      __syncthreads();
      if (tid == 0){
        float S = sred[0] + sred[2] + sred[4] + sred[6];
        float S2 = sred[1] + sred[3] + sred[5] + sred[7];
        part[(size_t)(b * 8 + (nt & 7)) * 8 + ot] = make_float2(S, S2);
      }
    }
  } else {
    float* out = (float*)outp;
    #pragma unroll
    for (int m = 0; m < 4; m++){
      int tl = t0 + wn * 64 + m * 16 + ((lane >> 4) * 4);
      #pragma unroll
      for (int n = 0; n < 4; n++){
        int o = ob + wo * 64 + n * 16 + (lane & 15);
        float bz = bias[o];
        size_t base = ((size_t)b * 1024 + o) * 1024 + tl;
        const unsigned short* xr = (const unsigned short*)resp;
        us4 xv = *(const us4*)&xr[base];
        f32x4 v;
        v[0] = bf2f(xv[0]); v[1] = bf2f(xv[1]); v[2] = bf2f(xv[2]); v[3] = bf2f(xv[3]);
        #pragma unroll
        for (int r = 0; r < 4; r++) v[r] += acc[m][n][r] + bz;
        *(f32x4*)&out[base] = v;
      }
    }
  }
}

// ---------------- flash attention v9: 128 q-rows, compact bias table, l via ones-MFMA ----------------
__global__ __launch_bounds__(256, 3) void attn_k9(
    const unsigned short* __restrict__ qkT,  // (B,T,2048): h*128 + [0..63]=q, [64..127]=k
    const unsigned short* __restrict__ vT,   // (B,16,64,1024) ch-major V
    const float* __restrict__ btab,          // (16, 2048), pre-scaled by 8*log2e
    unsigned short* __restrict__ aT)         // (B,T,1024)
{
  __shared__ __align__(16) unsigned short Kb[2][64 * 64];
  __shared__ __align__(16) unsigned short Vb[2][64 * 64];
  __shared__ __align__(16) unsigned short Pb[4][32 * 64];
  __shared__ __align__(16) float cblds[288];   // bias for n in [-144,143]
  const int tid = threadIdx.x, lane = tid & 63, w = tid >> 6;
  const int d0 = blockIdx.x;
  const int xcd = d0 & 7, slot = d0 >> 3;
  const int bh = xcd * 16 + (slot >> 3);
  const int qt = slot & 7;
  const int h = bh & 15, b = bh >> 4;
  const int q0b = qt * 128;
  const int q0 = q0b + w * 32;
  const unsigned short* qk = qkT + (size_t)b * 1024 * 2048 + h * 128;
  const unsigned short* vh = vT + ((size_t)(b * 16 + h)) * 64 * 1024;
  const int lc = lane & 15, lg = lane >> 4;

  const float bneg = btab[h * 2048 + 0];      // s > q side (n <= -50)
  const float bpos = btab[h * 2048 + 2046];   // s < q side (n >= 50)

  // compact bias slice: cblds[i] = bias(n = i - 144)
  if (tid < 288) cblds[tid] = btab[h * 2048 + 879 + tid];

  bf16x8 qf[2][2];
  #pragma unroll
  for (int m = 0; m < 2; m++){
    const unsigned short* qrow = qk + (size_t)(q0 + m * 16 + lc) * 2048;
    #pragma unroll
    for (int k2 = 0; k2 < 2; k2++)
      qf[m][k2] = *(const bf16x8*)&qrow[k2 * 32 + lg * 8];
  }
  bf16x8 onesf;
  {
    us8 u;
    #pragma unroll
    for (int j = 0; j < 8; j++) u[j] = 0x3F80;     // bf16 1.0
    onesf = *(bf16x8*)&u;
  }
  f32x4 oacc[2][4], lacc[2];
  #pragma unroll
  for (int m = 0; m < 2; m++){
    #pragma unroll
    for (int cb = 0; cb < 4; cb++) oacc[m][cb] = 0.f;
    lacc[m] = 0.f;
  }

  const int lr = lane >> 3, lb = lane & 7;
  const float qs = 0.18033688011112042f;   // 0.125 * log2(e)

  #pragma unroll
  for (int j = 0; j < 2; j++){
    int chunk = w * 2 + j;
    int row = chunk * 8 + lr;
    int gcol = (lb ^ (row & 7)) * 8;
    gll16(qk + 64 + (size_t)row * 2048 + gcol, &Kb[0][chunk * 512]);
    gll16(vh + (size_t)row * 1024 + gcol, &Vb[0][chunk * 512]);
  }
  __syncthreads();

  for (int t = 0; t < 16; ++t){
    const int cur = t & 1;
    const int st0 = t * 64;
    if (t < 15){
      int nst = st0 + 64;
      #pragma unroll
      for (int j = 0; j < 2; j++){
        int chunk = w * 2 + j;
        int row = chunk * 8 + lr;
        int gcol = (lb ^ (row & 7)) * 8;
        gll16(qk + 64 + (size_t)(nst + row) * 2048 + gcol, &Kb[cur ^ 1][chunk * 512]);
        gll16(vh + (size_t)row * 1024 + nst + gcol, &Vb[cur ^ 1][chunk * 512]);
      }
    }
    // swapped QK^T: lane holds q=lc (per m), s = sub*16 + lg*4 + r
    f32x4 sfr[2][4];
    #pragma unroll
    for (int m = 0; m < 2; m++)
      #pragma unroll
      for (int sub = 0; sub < 4; sub++) sfr[m][sub] = 0.f;
    __builtin_amdgcn_s_setprio(1);
    #pragma unroll
    for (int sub = 0; sub < 4; sub++){
      int row = sub * 16 + lc;
      #pragma unroll
      for (int k2 = 0; k2 < 2; k2++){
        int blk = (lg + k2 * 4) ^ (row & 7);
        bf16x8 bk = *(const bf16x8*)&Kb[cur][row * 64 + blk * 8];
        sfr[0][sub] = mfma16(bk, qf[0][k2], sfr[0][sub]);
        sfr[1][sub] = mfma16(bk, qf[1][k2], sfr[1][sub]);
      }
    }
    __builtin_amdgcn_s_setprio(0);
    // fixed-shift softmax: P = exp2(s*qs + bias); bounded logits, no max tracking, no VALU sum
    const bool unineg = (st0 >= q0 + 81);        // all n = q-s <= -50
    const bool unipos = (st0 + 113 <= q0);       // all n >= 50
    if (unineg || unipos){
      const float bc = unineg ? bneg : bpos;
      #pragma unroll
      for (int m = 0; m < 2; m++)
        #pragma unroll
        for (int sub = 0; sub < 4; sub++)
          #pragma unroll
          for (int r = 0; r < 4; r++)
            sfr[m][sub][r] = exp2f(fmaf(sfr[m][sub][r], qs, bc));
    } else {
      #pragma unroll
      for (int m = 0; m < 2; m++){
        // i = n + 144 = (q_global - s_global) + 144
        const float* bp = &cblds[(q0 + m * 16 + lc) - st0 + 144 - lg * 4];
        #pragma unroll
        for (int sub = 0; sub < 4; sub++)
          #pragma unroll
          for (int r = 0; r < 4; r++)
            sfr[m][sub][r] = exp2f(fmaf(sfr[m][sub][r], qs, bp[-(sub * 16) - r]));
      }
    }
    // P write: cvt_pk pairs + 8B stores, swizzled
    unsigned short* P = &Pb[w][0];
    #pragma unroll
    for (int m = 0; m < 2; m++){
      int qrow = m * 16 + lc;
      int rsw = (qrow & 7) << 3;
      #pragma unroll
      for (int sub = 0; sub < 4; sub++){
        int col = sub * 16 + lg * 4;
        unsigned w0, w1;
        asm("v_cvt_pk_bf16_f32 %0, %1, %2" : "=v"(w0) : "v"(sfr[m][sub][0]), "v"(sfr[m][sub][1]));
        asm("v_cvt_pk_bf16_f32 %0, %1, %2" : "=v"(w1) : "v"(sfr[m][sub][2]), "v"(sfr[m][sub][3]));
        uint2 pk; pk.x = w0; pk.y = w1;
        *(uint2*)&P[qrow * 64 + (col ^ rsw)] = pk;
      }
    }
    // PV + l accumulation (P · ones) via MFMA
    __builtin_amdgcn_s_setprio(1);
    #pragma unroll
    for (int k2 = 0; k2 < 2; k2++){
      bf16x8 pa[2];
      #pragma unroll
      for (int m = 0; m < 2; m++){
        int rowp = m * 16 + lc;
        int blkp = (lg + k2 * 4) ^ (rowp & 7);
        pa[m] = *(const bf16x8*)&P[rowp * 64 + blkp * 8];
      }
      #pragma unroll
      for (int cb = 0; cb < 4; cb++){
        int ch = cb * 16 + lc;
        int blkv = (lg + k2 * 4) ^ (ch & 7);
        bf16x8 bv = *(const bf16x8*)&Vb[cur][ch * 64 + blkv * 8];
        oacc[0][cb] = mfma16(pa[0], bv, oacc[0][cb]);
        oacc[1][cb] = mfma16(pa[1], bv, oacc[1][cb]);
      }
      lacc[0] = mfma16(pa[0], onesf, lacc[0]);
      lacc[1] = mfma16(pa[1], onesf, lacc[1]);
    }
    __builtin_amdgcn_s_setprio(0);
    __syncthreads();   // staged tile t+1 ready + buffer-reuse safety
  }
  #pragma unroll
  for (int m = 0; m < 2; m++)
    #pragma unroll
    for (int r = 0; r < 4; r++){
      float li = 1.0f / lacc[m][r];
      int tq = q0 + m * 16 + lg * 4 + r;
      #pragma unroll
      for (int cb = 0; cb < 4; cb++){
        int ch = h * 64 + cb * 16 + lc;
        aT[((size_t)b * 1024 + tq) * 1024 + ch] = f2bf(oacc[m][cb][r] * li);
      }
    }
}

// ---------------- launch ----------------
extern "C" void kernel_launch(void* const* d_in, const int* in_sizes, int n_in,
                              void* d_out, int out_size, void* d_ws, size_t ws_size,
                              hipStream_t stream)
{
  const float* x       = (const float*)d_in[0];
  const float* gn1_g   = (const float*)d_in[1];
  const float* gn1_b   = (const float*)d_in[2];
  const float* conv1_w = (const float*)d_in[3];
  const float* conv1_b = (const float*)d_in[4];
  const float* gn2_g   = (const float*)d_in[5];
  const float* gn2_b   = (const float*)d_in[6];
  const float* conv2_w = (const float*)d_in[7];
  const float* conv2_b = (const float*)d_in[8];
  const float* norm_g  = (const float*)d_in[9];
  const float* norm_b  = (const float*)d_in[10];
  const float* agn_g   = (const float*)d_in[11];
  const float* agn_b   = (const float*)d_in[12];
  const float* qkv_w   = (const float*)d_in[13];
  const float* qkv_b   = (const float*)d_in[14];
  const float* proj_w  = (const float*)d_in[15];
  const float* proj_b  = (const float*)d_in[16];
  const float* rel_emb = (const float*)d_in[17];

  if (ws_size < 139526144u) return;   // need ~133 MiB scratch

  char* ws = (char*)d_ws;
  unsigned short* w1p   = (unsigned short*)(ws + 0);
  unsigned short* w2p   = (unsigned short*)(ws + 6291456);
  unsigned short* wqkv  = (unsigned short*)(ws + 12582912);
  unsigned short* wproj = (unsigned short*)(ws + 18874368);
  float* btab           = (float*)(ws + 20971520);
  float2* stats1        = (float2*)(ws + 21102592);
  float2* part2n        = (float2*)(ws + 21110784);   // 2048 float2
  float2* part8n        = (float2*)(ws + 21127168);   // 512 float2
  float2* part32        = (float2*)(ws + 21131264);   // 1024 float2
  unsigned short* h1p   = (unsigned short*)(ws + 22020096);   // (B,1026,1024) bf16
  unsigned short* c1    = (unsigned short*)(ws + 38830080);   // (B,1024,1024) bf16
  unsigned short* g2p   = (unsigned short*)(ws + 55607296);   // (B,1026,1024) bf16
  unsigned short* qkT   = h1p;                                // reuse: (B,T,2048) bf16
  unsigned short* vT    = (unsigned short*)(ws + 55574528);   // (B,16,64,1024) bf16
  unsigned short* xb    = (unsigned short*)(ws + 72417280);   // (B,C,T) bf16; becomes x+h in-place
  unsigned short* attn_in = (unsigned short*)(ws + 72417280); // reuse after gn8 (xb dead)
  unsigned short* xin   = (unsigned short*)(ws + 105971712);  // (B,C,T) bf16 C-major
  unsigned short* aT    = (unsigned short*)(ws + 122748928);  // (B,T,C) bf16

  prep_all<<<12736, 256, 0, stream>>>(conv1_w, conv2_w, w1p, w2p,
                                      qkv_w, proj_w, wqkv, wproj,
                                      h1p, g2p, rel_emb, btab,
                                      x, stats1, xb);

  gn_apply_tr<1, 1, 1, 0><<<4096, 256, 0, stream>>>(xb, stats1, gn1_g, gn1_b, h1p);

  gemm_k<3, 0, 2><<<512, 256, 0, stream>>>(h1p, w1p, conv1_b, c1, nullptr, part2n, 1024, 64);
  gn2_apply<1><<<256, 256, 0, stream>>>(c1, part2n, gn2_g, gn2_b, g2p);

  // conv2 + residual, in-place on xb (bf16): xb <- conv2(g2p) + bias + xb, + GN8 partials
  gemm_k<3, 4, 8><<<512, 256, 0, stream>>>(g2p, w2p, conv2_b, xb, xb, part8n, 1024, 64);
  gn8_apply<<<1024, 256, 0, stream>>>(xb, part8n, norm_g, norm_b, xin, part32);

  gn_apply_tr<0, 1, 0, 1><<<4096, 256, 0, stream>>>(xin, part32, agn_g, agn_b, attn_in);

  gemm_k<1, 3, 0><<<1536, 256, 0, stream>>>(attn_in, wqkv, qkv_b, qkT, vT, nullptr, 3072, 64);

  attn_k9<<<1024, 256, 0, stream>>>(qkT, vT, btab, aT);

  gemm_k<1, 2, 0><<<512, 256, 0, stream>>>(aT, wproj, proj_b, d_out, xin, nullptr, 1024, 64);
}